// Round 1
// baseline (156.116 us; speedup 1.0000x reference)
//
#include <hip/hip_runtime.h>
#include <hip/hip_bf16.h>
#include <stdint.h>
#include <math.h>

#define KDIM 2304   // 9 * 256

typedef __attribute__((ext_vector_type(8))) short bf16x8;
typedef __attribute__((ext_vector_type(4))) float f32x4;

__device__ inline unsigned short f2bf(float f) {
  union { float f; unsigned int u; } v; v.f = f;
  unsigned int u = v.u;
  unsigned int r = (u + 0x7FFFu + ((u >> 16) & 1u)) >> 16;
  return (unsigned short)r;
}
__device__ inline float bf2f(unsigned short h) {
  union { unsigned int u; float f; } v; v.u = ((unsigned int)h) << 16;
  return v.f;
}

__device__ inline void gl2lds16(const void* g, void* l) {
  __builtin_amdgcn_global_load_lds((const __attribute__((address_space(1))) void*)g,
                                   (__attribute__((address_space(3))) void*)l,
                                   16, 0, 0);
}

// ---------------------------------------------------------------------------
// Kernel 1: x (B,C,H,W) fp32 -> xTb (B,H,W,C) bf16
// ---------------------------------------------------------------------------
__global__ __launch_bounds__(256) void k_transpose(const float* __restrict__ x,
                                                   unsigned short* __restrict__ xTb) {
  __shared__ float tile[32][33];
  int t = threadIdx.x;
  int tx = t & 31, ty = t >> 5;
  int p0 = blockIdx.x * 32;
  int c0 = blockIdx.y * 32;
  int b  = blockIdx.z;
  const float* xb = x + ((size_t)b << 20);
#pragma unroll
  for (int i = 0; i < 4; ++i) {
    int c = c0 + ty + i * 8;
    tile[ty + i * 8][tx] = xb[((size_t)c << 12) + p0 + tx];
  }
  __syncthreads();
  unsigned short* ob = xTb + ((size_t)b << 20);
#pragma unroll
  for (int i = 0; i < 4; ++i) {
    int p = p0 + ty + i * 8;
    ob[(((size_t)p) << 8) + c0 + tx] = f2bf(tile[tx][ty + i * 8]);
  }
}

// ---------------------------------------------------------------------------
// Kernel 2: weight prep (Wpk in A-fragment order; Wob; zero page).
// ---------------------------------------------------------------------------
__global__ __launch_bounds__(256) void k_wprep(const float* __restrict__ dcn_w,
                                               const float* __restrict__ offset_w,
                                               unsigned short* __restrict__ Wpk,
                                               unsigned short* __restrict__ Wob,
                                               unsigned short* __restrict__ zp) {
  int gid = blockIdx.x * 256 + threadIdx.x;
  const int N1 = 72 * 8192;
  const int N2 = 32 * KDIM;
  if (gid < N1) {
    int j = gid & 7;
    int lane = (gid >> 3) & 63;
    int mb = (gid >> 9) & 15;
    int kc = gid >> 13;
    int row = mb * 16 + (lane & 15);
    int gk = kc * 32 + ((lane >> 4) << 3) + j;
    int c = gk & 255, kidx = gk >> 8;
    Wpk[gid] = f2bf(dcn_w[((size_t)(row * 256 + c)) * 9 + kidx]);
  } else if (gid < N1 + N2) {
    int g = gid - N1;
    int ch = g / KDIM, k = g % KDIM;
    int kidx = k >> 8, c = k & 255;
    Wob[g] = (ch < 27) ? f2bf(offset_w[((size_t)(ch * 256 + c)) * 9 + kidx])
                       : (unsigned short)0;
  } else if (gid < N1 + N2 + 128) {
    zp[gid - N1 - N2] = 0;
  }
}

// ---------------------------------------------------------------------------
// Kernel 3: offset conv GEMM, split-K x2 (blockIdx.y = K-half).
//  Double-buffered LDS, counted vmcnt waits, raw s_barrier (loads stay in
//  flight across barriers -- no per-iteration vmcnt(0) drain).
// ---------------------------------------------------------------------------
__global__ __launch_bounds__(256) void k_offs_gemm(const unsigned short* __restrict__ xTb,
                                                   const unsigned short* __restrict__ Wob,
                                                   const unsigned short* __restrict__ zp,
                                                   float* __restrict__ O2p) {
  __shared__ unsigned short As[2][64 * 32];
  __shared__ unsigned short Bs[2][32 * 32];
  int t = threadIdx.x;
  int wv = t >> 6, lane = t & 63;
  int n0 = blockIdx.x * 64;
  int z = blockIdx.y;
  int r0 = t >> 2, coff = (t & 3) * 8;

  int rowA = n0 + r0;
  int b_ = rowA >> 12, hw = rowA & 4095, h = hw >> 6, w = hw & 63;

  f32x4 acc[2] = {};

  auto stage = [&](int kt, int buf) {
    int k0 = kt * 32;
    int kidx = k0 >> 8, c0 = k0 & 255;
    int di = kidx / 3 - 1, dj = kidx % 3 - 1;
    int y = h + di, xx = w + dj;
    const unsigned short* g = (y >= 0 && y < 64 && xx >= 0 && xx < 64)
        ? xTb + (((((size_t)b_) << 12) + (y << 6) + xx) << 8) + c0 + coff
        : zp;
    gl2lds16(g, (char*)As[buf] + wv * 1024);
    if (t < 128) {  // waves 0,1: also stage B (wave-uniform branch)
      const unsigned short* gB = Wob + (size_t)(t >> 2) * KDIM + k0 + coff;
      gl2lds16(gB, (char*)Bs[buf] + wv * 1024);
    }
  };

  int kbeg = z * 36, kend = kbeg + 36;
  stage(kbeg, 0);

  for (int kt = kbeg; kt < kend; ++kt) {
    int buf = (kt - kbeg) & 1;
    if (kt + 1 < kend) {
      stage(kt + 1, buf ^ 1);
      // wait: stage kt landed; stage kt+1 stays in flight.
      // waves 0-1 issue 2 gl2lds/stage, waves 2-3 issue 1.
      if (wv < 2) asm volatile("s_waitcnt vmcnt(2)" ::: "memory");
      else        asm volatile("s_waitcnt vmcnt(1)" ::: "memory");
    } else {
      asm volatile("s_waitcnt vmcnt(0)" ::: "memory");
    }
    asm volatile("s_barrier" ::: "memory");

    bf16x8 aF, bF[2];
    aF = *(const bf16x8*)(As[buf] + (wv * 16 + (lane & 15)) * 32 + (lane >> 4) * 8);
#pragma unroll
    for (int j = 0; j < 2; ++j)
      bF[j] = *(const bf16x8*)(Bs[buf] + (j * 16 + (lane & 15)) * 32 + (lane >> 4) * 8);
#pragma unroll
    for (int j = 0; j < 2; ++j)
      acc[j] = __builtin_amdgcn_mfma_f32_16x16x32_bf16(aF, bF[j], acc[j], 0, 0, 0);

    // all waves done reading buf before next iteration's stage overwrites it
    asm volatile("s_barrier" ::: "memory");
  }

  int quad = lane >> 4, cl = lane & 15;
  float* O2z = O2p + (size_t)z * 16384 * 32;
#pragma unroll
  for (int j = 0; j < 2; ++j) {
    int col = j * 16 + cl;
#pragma unroll
    for (int r = 0; r < 4; ++r) {
      int row = n0 + wv * 16 + quad * 4 + r;
      O2z[(size_t)row * 32 + col] = acc[j][r];
    }
  }
}

// ---------------------------------------------------------------------------
// Kernel 4: sampling weights/offsets table (sums split-K partials + bias).
// ---------------------------------------------------------------------------
__global__ __launch_bounds__(256) void k_sweights(const float* __restrict__ O2p,
                                                  const float* __restrict__ offb,
                                                  float* __restrict__ SW) {
  int gid = blockIdx.x * 256 + threadIdx.x;
  if (gid >= 9 * 16384) return;
  int k = gid >> 14;
  int bhw = gid & 16383;
  int h = (bhw >> 6) & 63, w = bhw & 63;

  const float* o0 = O2p + (size_t)bhw * 32;
  const float* o1 = o0 + (size_t)16384 * 32;
  float dy = o0[2 * k]     + o1[2 * k]     + offb[2 * k];
  float dx = o0[2 * k + 1] + o1[2 * k + 1] + offb[2 * k + 1];
  float mv = o0[18 + k]    + o1[18 + k]    + offb[18 + k];
  float mask = 1.0f / (1.0f + expf(-mv));

  float py = (float)(h - 1 + k / 3) + dy;
  float px = (float)(w - 1 + k % 3) + dx;
  float y0f = floorf(py), x0f = floorf(px);
  float wy = py - y0f, wx = px - x0f;
  int y0 = (int)y0f, x0 = (int)x0f;
  int y1 = y0 + 1, x1 = x0 + 1;

  float vy0 = (y0 >= 0 && y0 < 64) ? 1.f : 0.f;
  float vy1 = (y1 >= 0 && y1 < 64) ? 1.f : 0.f;
  float vx0 = (x0 >= 0 && x0 < 64) ? 1.f : 0.f;
  float vx1 = (x1 >= 0 && x1 < 64) ? 1.f : 0.f;
  int y0c = min(max(y0, 0), 63), y1c = min(max(y1, 0), 63);
  int x0c = min(max(x0, 0), 63), x1c = min(max(x1, 0), 63);

  float4 wv4;
  wv4.x = (1.f - wy) * (1.f - wx) * vy0 * vx0 * mask;
  wv4.y = (1.f - wy) * wx * vy0 * vx1 * mask;
  wv4.z = wy * (1.f - wx) * vy1 * vx0 * mask;
  wv4.w = wy * wx * vy1 * vx1 * mask;
  uint4 ov;
  ov.x = (unsigned)(((y0c << 6) + x0c) << 8);
  ov.y = (unsigned)(((y0c << 6) + x1c) << 8);
  ov.z = (unsigned)(((y1c << 6) + x0c) << 8);
  ov.w = (unsigned)(((y1c << 6) + x1c) << 8);

  float* p = SW + (size_t)gid * 8;
  *(float4*)p = wv4;
  *(uint4*)(p + 4) = ov;
}

// ---------------------------------------------------------------------------
// Kernel 5: fused sample + main GEMM, software-pipelined, 512 thr / 8 waves.
//  BM=256 x BN=64, BK=32, grid 256.
//  Raw s_barrier with lgkmcnt-only wait: prefetched gathers + A-fragment
//  loads stay in flight ACROSS the barrier (no vmcnt(0) drain per K-step).
//  SW table prefetched one k-group (7 iterations) ahead.
// ---------------------------------------------------------------------------
__global__ __launch_bounds__(512) void k_fused(const unsigned short* __restrict__ Wpk,
                                               const unsigned short* __restrict__ xTb,
                                               const float* __restrict__ SW,
                                               float* __restrict__ out) {
  __shared__ __align__(16) unsigned short Bs[2][64 * 40];  // 10 KB
  int t = threadIdx.x;
  int wv = t >> 6, lane = t & 63;
  int wm = wv & 3, wn = wv >> 2;
  int n0 = blockIdx.x * 64;
  int b  = n0 >> 12;
  const unsigned short* xb = xTb + ((size_t)b << 20);

  // sampling role: row r (0..63), channel quad g (0..7) -> ch = g*4
  int r = t >> 3, g = t & 7;
  int ch0 = g * 4;
  int bsw = r * 40 + ch0;

  // A-fragment base: wave covers m-blocks wm*4 .. wm*4+3
  const unsigned short* wpBase = Wpk + ((size_t)(wm * 4 * 64 + lane)) * 8;

  f32x4 acc[4][2] = {};

  float4 wv4; uint4 ov;
  {
    const float* sw = SW + ((size_t)(n0 + r)) * 8;
    wv4 = *(const float4*)sw;
    ov  = *(const uint4*)(sw + 4);
  }
  float4 wv4n = wv4; uint4 ovn = ov;
  ushort4 q00, q01, q10, q11;
  bf16x8 aF[4], aFn[4];

  // prologue: gathers + A for kt = 0
  {
    unsigned c = (unsigned)ch0;
    q00 = *(const ushort4*)(xb + ov.x + c);
    q01 = *(const ushort4*)(xb + ov.y + c);
    q10 = *(const ushort4*)(xb + ov.z + c);
    q11 = *(const ushort4*)(xb + ov.w + c);
#pragma unroll
    for (int i = 0; i < 4; ++i)
      aF[i] = *(const bf16x8*)(wpBase + (size_t)i * 512);
  }

#pragma unroll 2
  for (int kt = 0; kt < 72; ++kt) {
    // blend current gathers -> Bs[kt&1]
    float s[4];
    s[0] = wv4.x * bf2f(q00.x) + wv4.y * bf2f(q01.x) + wv4.z * bf2f(q10.x) + wv4.w * bf2f(q11.x);
    s[1] = wv4.x * bf2f(q00.y) + wv4.y * bf2f(q01.y) + wv4.z * bf2f(q10.y) + wv4.w * bf2f(q11.y);
    s[2] = wv4.x * bf2f(q00.z) + wv4.y * bf2f(q01.z) + wv4.z * bf2f(q10.z) + wv4.w * bf2f(q11.z);
    s[3] = wv4.x * bf2f(q00.w) + wv4.y * bf2f(q01.w) + wv4.z * bf2f(q10.w) + wv4.w * bf2f(q11.w);
    union { __hip_bfloat162 h2[2]; ushort4 v; } pk;
    pk.h2[0] = __float22bfloat162_rn(make_float2(s[0], s[1]));
    pk.h2[1] = __float22bfloat162_rn(make_float2(s[2], s[3]));
    *(ushort4*)(&Bs[kt & 1][bsw]) = pk.v;

    // SW group prefetch, 7 iterations ahead of first use
    if ((kt & 7) == 0 && kt < 64) {
      const float* swp = SW + ((size_t)((((kt >> 3) + 1) << 14) + n0 + r)) * 8;
      wv4n = *(const float4*)swp;
      ovn  = *(const uint4*)(swp + 4);
    }

    // prefetch kt+1 (stays in flight across the barrier below)
    if (kt < 71) {
      int kn = kt + 1;
      if ((kn & 7) == 0) { wv4 = wv4n; ov = ovn; }
      unsigned c = (unsigned)(((kn & 7) << 5) + ch0);
      q00 = *(const ushort4*)(xb + ov.x + c);
      q01 = *(const ushort4*)(xb + ov.y + c);
      q10 = *(const ushort4*)(xb + ov.z + c);
      q11 = *(const ushort4*)(xb + ov.w + c);
#pragma unroll
      for (int i = 0; i < 4; ++i)
        aFn[i] = *(const bf16x8*)(wpBase + ((size_t)kn * 16 + i) * 512);
    }

    // LDS writes visible, then barrier -- NO vmcnt drain (prefetch in flight)
    asm volatile("s_waitcnt lgkmcnt(0)\n\ts_barrier" ::: "memory");

    bf16x8 bF[2];
#pragma unroll
    for (int j = 0; j < 2; ++j)
      bF[j] = *(const bf16x8*)(&Bs[kt & 1][(wn * 32 + j * 16 + (lane & 15)) * 40 + (lane >> 4) * 8]);
#pragma unroll
    for (int i = 0; i < 4; ++i)
#pragma unroll
      for (int j = 0; j < 2; ++j)
        acc[i][j] = __builtin_amdgcn_mfma_f32_16x16x32_bf16(aF[i], bF[j], acc[i][j], 0, 0, 0);
    if (kt < 71) {
#pragma unroll
      for (int i = 0; i < 4; ++i) aF[i] = aFn[i];
    }
  }

  // epilogue
  int quad = lane >> 4, cl = lane & 15;
  float* ob = out + (((size_t)b) << 20);
#pragma unroll
  for (int i = 0; i < 4; ++i) {
    int mbase = wm * 64 + i * 16 + quad * 4;
#pragma unroll
    for (int j = 0; j < 2; ++j) {
      int hw = (n0 & 4095) + wn * 32 + j * 16 + cl;
      float* op = ob + hw;
#pragma unroll
      for (int rr = 0; rr < 4; ++rr)
        op[((size_t)(mbase + rr)) << 12] = acc[i][j][rr];
    }
  }
}

// ---------------------------------------------------------------------------
extern "C" void kernel_launch(void* const* d_in, const int* in_sizes, int n_in,
                              void* d_out, int out_size, void* d_ws, size_t ws_size,
                              hipStream_t stream) {
  const float* x        = (const float*)d_in[0];
  const float* offset_w = (const float*)d_in[1];
  const float* offset_b = (const float*)d_in[2];
  const float* dcn_w    = (const float*)d_in[3];
  float* out = (float*)d_out;

  char* ws = (char*)d_ws;
  size_t off = 0;
  auto carve = [&](size_t bytes) -> void* {
    void* p = ws + off;
    off += (bytes + 255) & ~(size_t)255;
    return p;
  };
  unsigned short* xTb = (unsigned short*)carve(4ull * 64 * 64 * 256 * 2);   // 8 MB
  unsigned short* Wpk = (unsigned short*)carve(72ull * 8192 * 2);           // 1.125 MB
  unsigned short* Wob = (unsigned short*)carve(32ull * KDIM * 2);           // 144 KB
  unsigned short* zp  = (unsigned short*)carve(256);                        // zero page
  float*          O2p = (float*)carve(2ull * 16384 * 32 * 4);               // 4 MB
  float*          SW  = (float*)carve(9ull * 16384 * 8 * 4);                // 4.5 MB
  (void)ws_size; (void)in_sizes; (void)n_in; (void)out_size;

  k_transpose<<<dim3(128, 8, 4), 256, 0, stream>>>(x, xTb);
  k_wprep<<<dim3((72 * 8192 + 32 * KDIM + 128 + 255) / 256), 256, 0, stream>>>(
      dcn_w, offset_w, Wpk, Wob, zp);
  k_offs_gemm<<<dim3(256, 2), 256, 0, stream>>>(xTb, Wob, zp, O2p);
  k_sweights<<<dim3((9 * 16384 + 255) / 256), 256, 0, stream>>>(O2p, offset_b, SW);
  k_fused<<<dim3(256), 512, 0, stream>>>(Wpk, xTb, SW, out);
}

// Round 2
// 149.595 us; speedup vs baseline: 1.0436x; 1.0436x over previous
//
#include <hip/hip_runtime.h>
#include <hip/hip_bf16.h>
#include <stdint.h>
#include <math.h>

#define KDIM 2304   // 9 * 256

typedef __attribute__((ext_vector_type(8))) short bf16x8;
typedef __attribute__((ext_vector_type(4))) float f32x4;

__device__ inline unsigned short f2bf(float f) {
  union { float f; unsigned int u; } v; v.f = f;
  unsigned int u = v.u;
  unsigned int r = (u + 0x7FFFu + ((u >> 16) & 1u)) >> 16;
  return (unsigned short)r;
}
__device__ inline float bf2f(unsigned short h) {
  union { unsigned int u; float f; } v; v.u = ((unsigned int)h) << 16;
  return v.f;
}

__device__ inline void gl2lds16(const void* g, void* l) {
  __builtin_amdgcn_global_load_lds((const __attribute__((address_space(1))) void*)g,
                                   (__attribute__((address_space(3))) void*)l,
                                   16, 0, 0);
}

// ---------------------------------------------------------------------------
// Kernel 1: x (B,C,H,W) fp32 -> xTb (B,H,W,C) bf16
// ---------------------------------------------------------------------------
__global__ __launch_bounds__(256) void k_transpose(const float* __restrict__ x,
                                                   unsigned short* __restrict__ xTb) {
  __shared__ float tile[32][33];
  int t = threadIdx.x;
  int tx = t & 31, ty = t >> 5;
  int p0 = blockIdx.x * 32;
  int c0 = blockIdx.y * 32;
  int b  = blockIdx.z;
  const float* xb = x + ((size_t)b << 20);
#pragma unroll
  for (int i = 0; i < 4; ++i) {
    int c = c0 + ty + i * 8;
    tile[ty + i * 8][tx] = xb[((size_t)c << 12) + p0 + tx];
  }
  __syncthreads();
  unsigned short* ob = xTb + ((size_t)b << 20);
#pragma unroll
  for (int i = 0; i < 4; ++i) {
    int p = p0 + ty + i * 8;
    ob[(((size_t)p) << 8) + c0 + tx] = f2bf(tile[tx][ty + i * 8]);
  }
}

// ---------------------------------------------------------------------------
// Kernel 2: weight prep (Wpk in A-fragment order; Wob; zero page).
// ---------------------------------------------------------------------------
__global__ __launch_bounds__(256) void k_wprep(const float* __restrict__ dcn_w,
                                               const float* __restrict__ offset_w,
                                               unsigned short* __restrict__ Wpk,
                                               unsigned short* __restrict__ Wob,
                                               unsigned short* __restrict__ zp) {
  int gid = blockIdx.x * 256 + threadIdx.x;
  const int N1 = 72 * 8192;
  const int N2 = 32 * KDIM;
  if (gid < N1) {
    int j = gid & 7;
    int lane = (gid >> 3) & 63;
    int mb = (gid >> 9) & 15;
    int kc = gid >> 13;
    int row = mb * 16 + (lane & 15);
    int gk = kc * 32 + ((lane >> 4) << 3) + j;
    int c = gk & 255, kidx = gk >> 8;
    Wpk[gid] = f2bf(dcn_w[((size_t)(row * 256 + c)) * 9 + kidx]);
  } else if (gid < N1 + N2) {
    int g = gid - N1;
    int ch = g / KDIM, k = g % KDIM;
    int kidx = k >> 8, c = k & 255;
    Wob[g] = (ch < 27) ? f2bf(offset_w[((size_t)(ch * 256 + c)) * 9 + kidx])
                       : (unsigned short)0;
  } else if (gid < N1 + N2 + 128) {
    zp[gid - N1 - N2] = 0;
  }
}

// ---------------------------------------------------------------------------
// Kernel 3: offset conv GEMM, split-K x2 (blockIdx.y = K-half).
//  Double-buffered LDS, counted vmcnt waits, raw s_barrier, XCD swizzle.
// ---------------------------------------------------------------------------
__global__ __launch_bounds__(256) void k_offs_gemm(const unsigned short* __restrict__ xTb,
                                                   const unsigned short* __restrict__ Wob,
                                                   const unsigned short* __restrict__ zp,
                                                   float* __restrict__ O2p) {
  __shared__ unsigned short As[2][64 * 32];
  __shared__ unsigned short Bs[2][32 * 32];
  int t = threadIdx.x;
  int wv = t >> 6, lane = t & 63;
  int bid = (int)blockIdx.x;
  int swz = (bid & 7) * 32 + (bid >> 3);   // XCD-contiguous chunks (256 = 8*32)
  int n0 = swz * 64;
  int z = blockIdx.y;
  int r0 = t >> 2, coff = (t & 3) * 8;

  int rowA = n0 + r0;
  int b_ = rowA >> 12, hw = rowA & 4095, h = hw >> 6, w = hw & 63;

  f32x4 acc[2] = {};

  auto stage = [&](int kt, int buf) {
    int k0 = kt * 32;
    int kidx = k0 >> 8, c0 = k0 & 255;
    int di = kidx / 3 - 1, dj = kidx % 3 - 1;
    int y = h + di, xx = w + dj;
    const unsigned short* g = (y >= 0 && y < 64 && xx >= 0 && xx < 64)
        ? xTb + (((((size_t)b_) << 12) + (y << 6) + xx) << 8) + c0 + coff
        : zp;
    gl2lds16(g, (char*)As[buf] + wv * 1024);
    if (t < 128) {  // waves 0,1: also stage B (wave-uniform branch)
      const unsigned short* gB = Wob + (size_t)(t >> 2) * KDIM + k0 + coff;
      gl2lds16(gB, (char*)Bs[buf] + wv * 1024);
    }
  };

  int kbeg = z * 36, kend = kbeg + 36;
  stage(kbeg, 0);

  for (int kt = kbeg; kt < kend; ++kt) {
    int buf = (kt - kbeg) & 1;
    if (kt + 1 < kend) {
      stage(kt + 1, buf ^ 1);
      // wait: stage kt landed; stage kt+1 stays in flight.
      if (wv < 2) asm volatile("s_waitcnt vmcnt(2)" ::: "memory");
      else        asm volatile("s_waitcnt vmcnt(1)" ::: "memory");
    } else {
      asm volatile("s_waitcnt vmcnt(0)" ::: "memory");
    }
    asm volatile("s_barrier" ::: "memory");

    bf16x8 aF, bF[2];
    aF = *(const bf16x8*)(As[buf] + (wv * 16 + (lane & 15)) * 32 + (lane >> 4) * 8);
#pragma unroll
    for (int j = 0; j < 2; ++j)
      bF[j] = *(const bf16x8*)(Bs[buf] + (j * 16 + (lane & 15)) * 32 + (lane >> 4) * 8);
#pragma unroll
    for (int j = 0; j < 2; ++j)
      acc[j] = __builtin_amdgcn_mfma_f32_16x16x32_bf16(aF, bF[j], acc[j], 0, 0, 0);

    asm volatile("s_barrier" ::: "memory");
  }

  int quad = lane >> 4, cl = lane & 15;
  float* O2z = O2p + (size_t)z * 16384 * 32;
#pragma unroll
  for (int j = 0; j < 2; ++j) {
    int col = j * 16 + cl;
#pragma unroll
    for (int r = 0; r < 4; ++r) {
      int row = n0 + wv * 16 + quad * 4 + r;
      O2z[(size_t)row * 32 + col] = acc[j][r];
    }
  }
}

// ---------------------------------------------------------------------------
// Kernel 4: sampling weights/offsets table (sums split-K partials + bias).
// ---------------------------------------------------------------------------
__global__ __launch_bounds__(256) void k_sweights(const float* __restrict__ O2p,
                                                  const float* __restrict__ offb,
                                                  float* __restrict__ SW) {
  int gid = blockIdx.x * 256 + threadIdx.x;
  if (gid >= 9 * 16384) return;
  int k = gid >> 14;
  int bhw = gid & 16383;
  int h = (bhw >> 6) & 63, w = bhw & 63;

  const float* o0 = O2p + (size_t)bhw * 32;
  const float* o1 = o0 + (size_t)16384 * 32;
  float dy = o0[2 * k]     + o1[2 * k]     + offb[2 * k];
  float dx = o0[2 * k + 1] + o1[2 * k + 1] + offb[2 * k + 1];
  float mv = o0[18 + k]    + o1[18 + k]    + offb[18 + k];
  float mask = 1.0f / (1.0f + expf(-mv));

  float py = (float)(h - 1 + k / 3) + dy;
  float px = (float)(w - 1 + k % 3) + dx;
  float y0f = floorf(py), x0f = floorf(px);
  float wy = py - y0f, wx = px - x0f;
  int y0 = (int)y0f, x0 = (int)x0f;
  int y1 = y0 + 1, x1 = x0 + 1;

  float vy0 = (y0 >= 0 && y0 < 64) ? 1.f : 0.f;
  float vy1 = (y1 >= 0 && y1 < 64) ? 1.f : 0.f;
  float vx0 = (x0 >= 0 && x0 < 64) ? 1.f : 0.f;
  float vx1 = (x1 >= 0 && x1 < 64) ? 1.f : 0.f;
  int y0c = min(max(y0, 0), 63), y1c = min(max(y1, 0), 63);
  int x0c = min(max(x0, 0), 63), x1c = min(max(x1, 0), 63);

  float4 wv4;
  wv4.x = (1.f - wy) * (1.f - wx) * vy0 * vx0 * mask;
  wv4.y = (1.f - wy) * wx * vy0 * vx1 * mask;
  wv4.z = wy * (1.f - wx) * vy1 * vx0 * mask;
  wv4.w = wy * wx * vy1 * vx1 * mask;
  uint4 ov;
  ov.x = (unsigned)(((y0c << 6) + x0c) << 8);
  ov.y = (unsigned)(((y0c << 6) + x1c) << 8);
  ov.z = (unsigned)(((y1c << 6) + x0c) << 8);
  ov.w = (unsigned)(((y1c << 6) + x1c) << 8);

  float* p = SW + (size_t)gid * 8;
  *(float4*)p = wv4;
  *(uint4*)(p + 4) = ov;
}

// ---------------------------------------------------------------------------
// Kernel 5: fused sample + main GEMM, DEPTH-2 software pipeline, 512 thr.
//  BM=256 x BN=64, BK=32, grid 256, XCD-swizzled blocks.
//  Gathers + A-fragments for kt+2 issued at kt; loads span two raw
//  s_barriers (lgkmcnt-only wait, no vmcnt drain).
// ---------------------------------------------------------------------------
#define FSTEP(KT, Q, AF, BUF, DOSW)                                            \
  do {                                                                         \
    float s0_ = wv4.x * bf2f(Q[0].x) + wv4.y * bf2f(Q[1].x) +                  \
                wv4.z * bf2f(Q[2].x) + wv4.w * bf2f(Q[3].x);                   \
    float s1_ = wv4.x * bf2f(Q[0].y) + wv4.y * bf2f(Q[1].y) +                  \
                wv4.z * bf2f(Q[2].y) + wv4.w * bf2f(Q[3].y);                   \
    float s2_ = wv4.x * bf2f(Q[0].z) + wv4.y * bf2f(Q[1].z) +                  \
                wv4.z * bf2f(Q[2].z) + wv4.w * bf2f(Q[3].z);                   \
    float s3_ = wv4.x * bf2f(Q[0].w) + wv4.y * bf2f(Q[1].w) +                  \
                wv4.z * bf2f(Q[2].w) + wv4.w * bf2f(Q[3].w);                   \
    union { __hip_bfloat162 h2[2]; ushort4 v; } pk_;                           \
    pk_.h2[0] = __float22bfloat162_rn(make_float2(s0_, s1_));                  \
    pk_.h2[1] = __float22bfloat162_rn(make_float2(s2_, s3_));                  \
    *(ushort4*)(&Bs[BUF][bsw]) = pk_.v;                                        \
    if (DOSW && ((KT) & 7) == 0 && (KT) < 64) {                                \
      const float* swp_ =                                                      \
          SW + ((size_t)(((((KT) >> 3) + 1) << 14) + n0 + r)) * 8;             \
      wv4n = *(const float4*)swp_;                                             \
      ovn  = *(const uint4*)(swp_ + 4);                                        \
    }                                                                          \
    if ((KT) < 70) {                                                           \
      int kn_ = (KT) + 2;                                                      \
      uint4 o_ = (((KT) & 7) >= 6) ? ovn : ov;                                 \
      unsigned c_ = (unsigned)(((kn_ & 7) << 5) + ch0);                        \
      Q[0] = *(const ushort4*)(xb + o_.x + c_);                                \
      Q[1] = *(const ushort4*)(xb + o_.y + c_);                                \
      Q[2] = *(const ushort4*)(xb + o_.z + c_);                                \
      Q[3] = *(const ushort4*)(xb + o_.w + c_);                                \
    }                                                                          \
    asm volatile("s_waitcnt lgkmcnt(0)\n\ts_barrier" ::: "memory");            \
    bf16x8 bF0_ = *(const bf16x8*)(&Bs[BUF][(wn * 32 + (lane & 15)) * 40 +     \
                                            (lane >> 4) * 8]);                 \
    bf16x8 bF1_ = *(const bf16x8*)(&Bs[BUF][(wn * 32 + 16 + (lane & 15)) * 40 +\
                                            (lane >> 4) * 8]);                 \
    _Pragma("unroll")                                                          \
    for (int i_ = 0; i_ < 4; ++i_) {                                           \
      acc[i_][0] =                                                             \
          __builtin_amdgcn_mfma_f32_16x16x32_bf16(AF[i_], bF0_, acc[i_][0],    \
                                                  0, 0, 0);                    \
      acc[i_][1] =                                                             \
          __builtin_amdgcn_mfma_f32_16x16x32_bf16(AF[i_], bF1_, acc[i_][1],    \
                                                  0, 0, 0);                    \
    }                                                                          \
    if ((KT) < 70) {                                                           \
      int kn_ = (KT) + 2;                                                      \
      _Pragma("unroll")                                                        \
      for (int i_ = 0; i_ < 4; ++i_)                                           \
        AF[i_] = *(const bf16x8*)(wpBase + ((size_t)kn_ * 16 + i_) * 512);     \
    }                                                                          \
  } while (0)

__global__ __launch_bounds__(512) void k_fused(const unsigned short* __restrict__ Wpk,
                                               const unsigned short* __restrict__ xTb,
                                               const float* __restrict__ SW,
                                               float* __restrict__ out) {
  __shared__ __align__(16) unsigned short Bs[2][64 * 40];  // 10 KB
  int t = threadIdx.x;
  int wv = t >> 6, lane = t & 63;
  int wm = wv & 3, wn = wv >> 2;
  int bid = (int)blockIdx.x;
  int swz = (bid & 7) * 32 + (bid >> 3);   // XCD-contiguous chunks (256 = 8*32)
  int n0 = swz * 64;
  int b  = n0 >> 12;
  const unsigned short* xb = xTb + ((size_t)b << 20);

  // sampling role: row r (0..63), channel quad g (0..7) -> ch = g*4
  int r = t >> 3, g = t & 7;
  int ch0 = g * 4;
  int bsw = r * 40 + ch0;

  // A-fragment base: wave covers m-blocks wm*4 .. wm*4+3
  const unsigned short* wpBase = Wpk + ((size_t)(wm * 4 * 64 + lane)) * 8;

  f32x4 acc[4][2] = {};

  float4 wv4, wv4n; uint4 ov, ovn;
  {
    const float* sw = SW + ((size_t)(n0 + r)) * 8;
    wv4 = *(const float4*)sw;
    ov  = *(const uint4*)(sw + 4);
  }
  wv4n = wv4; ovn = ov;

  ushort4 qA[4], qB[4];
  bf16x8 aFA[4], aFB[4];

  // prologue: gathers for kt=0 (qA) and kt=1 (qB); A-fragments for kt=0,1
  {
    unsigned c0_ = (unsigned)ch0;
    qA[0] = *(const ushort4*)(xb + ov.x + c0_);
    qA[1] = *(const ushort4*)(xb + ov.y + c0_);
    qA[2] = *(const ushort4*)(xb + ov.z + c0_);
    qA[3] = *(const ushort4*)(xb + ov.w + c0_);
    unsigned c1_ = (unsigned)(32 + ch0);
    qB[0] = *(const ushort4*)(xb + ov.x + c1_);
    qB[1] = *(const ushort4*)(xb + ov.y + c1_);
    qB[2] = *(const ushort4*)(xb + ov.z + c1_);
    qB[3] = *(const ushort4*)(xb + ov.w + c1_);
#pragma unroll
    for (int i = 0; i < 4; ++i) {
      aFA[i] = *(const bf16x8*)(wpBase + (size_t)i * 512);
      aFB[i] = *(const bf16x8*)(wpBase + (size_t)(16 + i) * 512);
    }
  }

  for (int kt = 0; kt < 72; kt += 2) {
    FSTEP(kt,     qA, aFA, 0, 1);
    FSTEP(kt + 1, qB, aFB, 1, 0);
    if ((kt & 7) == 6) { wv4 = wv4n; ov = ovn; }  // rotate after group end
  }

  // epilogue
  int quad = lane >> 4, cl = lane & 15;
  float* ob = out + (((size_t)b) << 20);
#pragma unroll
  for (int i = 0; i < 4; ++i) {
    int mbase = wm * 64 + i * 16 + quad * 4;
#pragma unroll
    for (int j = 0; j < 2; ++j) {
      int hw = (n0 & 4095) + wn * 32 + j * 16 + cl;
      float* op = ob + hw;
#pragma unroll
      for (int rr = 0; rr < 4; ++rr)
        op[((size_t)(mbase + rr)) << 12] = acc[i][j][rr];
    }
  }
}

// ---------------------------------------------------------------------------
extern "C" void kernel_launch(void* const* d_in, const int* in_sizes, int n_in,
                              void* d_out, int out_size, void* d_ws, size_t ws_size,
                              hipStream_t stream) {
  const float* x        = (const float*)d_in[0];
  const float* offset_w = (const float*)d_in[1];
  const float* offset_b = (const float*)d_in[2];
  const float* dcn_w    = (const float*)d_in[3];
  float* out = (float*)d_out;

  char* ws = (char*)d_ws;
  size_t off = 0;
  auto carve = [&](size_t bytes) -> void* {
    void* p = ws + off;
    off += (bytes + 255) & ~(size_t)255;
    return p;
  };
  unsigned short* xTb = (unsigned short*)carve(4ull * 64 * 64 * 256 * 2);   // 8 MB
  unsigned short* Wpk = (unsigned short*)carve(72ull * 8192 * 2);           // 1.125 MB
  unsigned short* Wob = (unsigned short*)carve(32ull * KDIM * 2);           // 144 KB
  unsigned short* zp  = (unsigned short*)carve(256);                        // zero page
  float*          O2p = (float*)carve(2ull * 16384 * 32 * 4);               // 4 MB
  float*          SW  = (float*)carve(9ull * 16384 * 8 * 4);                // 4.5 MB
  (void)ws_size; (void)in_sizes; (void)n_in; (void)out_size;

  k_transpose<<<dim3(128, 8, 4), 256, 0, stream>>>(x, xTb);
  k_wprep<<<dim3((72 * 8192 + 32 * KDIM + 128 + 255) / 256), 256, 0, stream>>>(
      dcn_w, offset_w, Wpk, Wob, zp);
  k_offs_gemm<<<dim3(256, 2), 256, 0, stream>>>(xTb, Wob, zp, O2p);
  k_sweights<<<dim3((9 * 16384 + 255) / 256), 256, 0, stream>>>(O2p, offset_b, SW);
  k_fused<<<dim3(256), 512, 0, stream>>>(Wpk, xTb, SW, out);
}

// Round 3
// 149.563 us; speedup vs baseline: 1.0438x; 1.0002x over previous
//
#include <hip/hip_runtime.h>
#include <hip/hip_bf16.h>
#include <stdint.h>
#include <math.h>

#define KDIM 2304   // 9 * 256

typedef __attribute__((ext_vector_type(8))) short bf16x8;
typedef __attribute__((ext_vector_type(4))) float f32x4;

__device__ inline unsigned short f2bf(float f) {
  union { float f; unsigned int u; } v; v.f = f;
  unsigned int u = v.u;
  unsigned int r = (u + 0x7FFFu + ((u >> 16) & 1u)) >> 16;
  return (unsigned short)r;
}
__device__ inline float bf2f(unsigned short h) {
  union { unsigned int u; float f; } v; v.u = ((unsigned int)h) << 16;
  return v.f;
}

__device__ inline void gl2lds16(const void* g, void* l) {
  __builtin_amdgcn_global_load_lds((const __attribute__((address_space(1))) void*)g,
                                   (__attribute__((address_space(3))) void*)l,
                                   16, 0, 0);
}

// ---------------------------------------------------------------------------
// Kernel 1: x (B,C,H,W) fp32 -> xTb (B,H,W,C) bf16
// ---------------------------------------------------------------------------
__global__ __launch_bounds__(256) void k_transpose(const float* __restrict__ x,
                                                   unsigned short* __restrict__ xTb) {
  __shared__ float tile[32][33];
  int t = threadIdx.x;
  int tx = t & 31, ty = t >> 5;
  int p0 = blockIdx.x * 32;
  int c0 = blockIdx.y * 32;
  int b  = blockIdx.z;
  const float* xb = x + ((size_t)b << 20);
#pragma unroll
  for (int i = 0; i < 4; ++i) {
    int c = c0 + ty + i * 8;
    tile[ty + i * 8][tx] = xb[((size_t)c << 12) + p0 + tx];
  }
  __syncthreads();
  unsigned short* ob = xTb + ((size_t)b << 20);
#pragma unroll
  for (int i = 0; i < 4; ++i) {
    int p = p0 + ty + i * 8;
    ob[(((size_t)p) << 8) + c0 + tx] = f2bf(tile[tx][ty + i * 8]);
  }
}

// ---------------------------------------------------------------------------
// Kernel 2: weight prep (Wpk in A-fragment order; Wob; zero page).
// ---------------------------------------------------------------------------
__global__ __launch_bounds__(256) void k_wprep(const float* __restrict__ dcn_w,
                                               const float* __restrict__ offset_w,
                                               unsigned short* __restrict__ Wpk,
                                               unsigned short* __restrict__ Wob,
                                               unsigned short* __restrict__ zp) {
  int gid = blockIdx.x * 256 + threadIdx.x;
  const int N1 = 72 * 8192;
  const int N2 = 32 * KDIM;
  if (gid < N1) {
    int j = gid & 7;
    int lane = (gid >> 3) & 63;
    int mb = (gid >> 9) & 15;
    int kc = gid >> 13;
    int row = mb * 16 + (lane & 15);
    int gk = kc * 32 + ((lane >> 4) << 3) + j;
    int c = gk & 255, kidx = gk >> 8;
    Wpk[gid] = f2bf(dcn_w[((size_t)(row * 256 + c)) * 9 + kidx]);
  } else if (gid < N1 + N2) {
    int g = gid - N1;
    int ch = g / KDIM, k = g % KDIM;
    int kidx = k >> 8, c = k & 255;
    Wob[g] = (ch < 27) ? f2bf(offset_w[((size_t)(ch * 256 + c)) * 9 + kidx])
                       : (unsigned short)0;
  } else if (gid < N1 + N2 + 128) {
    zp[gid - N1 - N2] = 0;
  }
}

// ---------------------------------------------------------------------------
// Kernel 3: offset conv GEMM, split-K x2 (blockIdx.y = K-half).
//  Double-buffered LDS, counted vmcnt waits, raw s_barrier, XCD swizzle.
// ---------------------------------------------------------------------------
__global__ __launch_bounds__(256) void k_offs_gemm(const unsigned short* __restrict__ xTb,
                                                   const unsigned short* __restrict__ Wob,
                                                   const unsigned short* __restrict__ zp,
                                                   float* __restrict__ O2p) {
  __shared__ unsigned short As[2][64 * 32];
  __shared__ unsigned short Bs[2][32 * 32];
  int t = threadIdx.x;
  int wv = t >> 6, lane = t & 63;
  int bid = (int)blockIdx.x;
  int swz = (bid & 7) * 32 + (bid >> 3);   // XCD-contiguous chunks (256 = 8*32)
  int n0 = swz * 64;
  int z = blockIdx.y;
  int r0 = t >> 2, coff = (t & 3) * 8;

  int rowA = n0 + r0;
  int b_ = rowA >> 12, hw = rowA & 4095, h = hw >> 6, w = hw & 63;

  f32x4 acc[2] = {};

  auto stage = [&](int kt, int buf) {
    int k0 = kt * 32;
    int kidx = k0 >> 8, c0 = k0 & 255;
    int di = kidx / 3 - 1, dj = kidx % 3 - 1;
    int y = h + di, xx = w + dj;
    const unsigned short* g = (y >= 0 && y < 64 && xx >= 0 && xx < 64)
        ? xTb + (((((size_t)b_) << 12) + (y << 6) + xx) << 8) + c0 + coff
        : zp;
    gl2lds16(g, (char*)As[buf] + wv * 1024);
    if (t < 128) {  // waves 0,1: also stage B (wave-uniform branch)
      const unsigned short* gB = Wob + (size_t)(t >> 2) * KDIM + k0 + coff;
      gl2lds16(gB, (char*)Bs[buf] + wv * 1024);
    }
  };

  int kbeg = z * 36, kend = kbeg + 36;
  stage(kbeg, 0);

  for (int kt = kbeg; kt < kend; ++kt) {
    int buf = (kt - kbeg) & 1;
    if (kt + 1 < kend) {
      stage(kt + 1, buf ^ 1);
      // wait: stage kt landed; stage kt+1 stays in flight.
      if (wv < 2) asm volatile("s_waitcnt vmcnt(2)" ::: "memory");
      else        asm volatile("s_waitcnt vmcnt(1)" ::: "memory");
    } else {
      asm volatile("s_waitcnt vmcnt(0)" ::: "memory");
    }
    asm volatile("s_barrier" ::: "memory");

    bf16x8 aF, bF[2];
    aF = *(const bf16x8*)(As[buf] + (wv * 16 + (lane & 15)) * 32 + (lane >> 4) * 8);
#pragma unroll
    for (int j = 0; j < 2; ++j)
      bF[j] = *(const bf16x8*)(Bs[buf] + (j * 16 + (lane & 15)) * 32 + (lane >> 4) * 8);
#pragma unroll
    for (int j = 0; j < 2; ++j)
      acc[j] = __builtin_amdgcn_mfma_f32_16x16x32_bf16(aF, bF[j], acc[j], 0, 0, 0);

    asm volatile("s_barrier" ::: "memory");
  }

  int quad = lane >> 4, cl = lane & 15;
  float* O2z = O2p + (size_t)z * 16384 * 32;
#pragma unroll
  for (int j = 0; j < 2; ++j) {
    int col = j * 16 + cl;
#pragma unroll
    for (int r = 0; r < 4; ++r) {
      int row = n0 + wv * 16 + quad * 4 + r;
      O2z[(size_t)row * 32 + col] = acc[j][r];
    }
  }
}

// ---------------------------------------------------------------------------
// Kernel 4: sampling weights/offsets table.
//  Coalesced: stage 32 O2p row-sums via LDS (float4 loads), then 288 outputs.
// ---------------------------------------------------------------------------
__global__ __launch_bounds__(256) void k_sweights(const float* __restrict__ O2p,
                                                  const float* __restrict__ offb,
                                                  float* __restrict__ SW) {
  __shared__ float os[32][33];
  int t = threadIdx.x;
  int bhw0 = blockIdx.x * 32;
  {
    int row = t >> 3, c4 = t & 7;   // 256 threads = 32 rows x 8 float4
    const float4* p0 = (const float4*)(O2p + (size_t)(bhw0 + row) * 32) + c4;
    const float4* p1 = (const float4*)(O2p + (size_t)(16384 + bhw0 + row) * 32) + c4;
    float4 a = *p0, b = *p1;
    os[row][c4 * 4 + 0] = a.x + b.x;
    os[row][c4 * 4 + 1] = a.y + b.y;
    os[row][c4 * 4 + 2] = a.z + b.z;
    os[row][c4 * 4 + 3] = a.w + b.w;
  }
  __syncthreads();
  for (int item = t; item < 288; item += 256) {
    int bl = item & 31, k = item >> 5;
    int bhw = bhw0 + bl;
    int h = (bhw >> 6) & 63, w = bhw & 63;
    float dy = os[bl][2 * k]     + offb[2 * k];
    float dx = os[bl][2 * k + 1] + offb[2 * k + 1];
    float mv = os[bl][18 + k]    + offb[18 + k];
    float mask = 1.0f / (1.0f + expf(-mv));

    float py = (float)(h - 1 + k / 3) + dy;
    float px = (float)(w - 1 + k % 3) + dx;
    float y0f = floorf(py), x0f = floorf(px);
    float wy = py - y0f, wx = px - x0f;
    int y0 = (int)y0f, x0 = (int)x0f;
    int y1 = y0 + 1, x1 = x0 + 1;

    float vy0 = (y0 >= 0 && y0 < 64) ? 1.f : 0.f;
    float vy1 = (y1 >= 0 && y1 < 64) ? 1.f : 0.f;
    float vx0 = (x0 >= 0 && x0 < 64) ? 1.f : 0.f;
    float vx1 = (x1 >= 0 && x1 < 64) ? 1.f : 0.f;
    int y0c = min(max(y0, 0), 63), y1c = min(max(y1, 0), 63);
    int x0c = min(max(x0, 0), 63), x1c = min(max(x1, 0), 63);

    float4 wv4;
    wv4.x = (1.f - wy) * (1.f - wx) * vy0 * vx0 * mask;
    wv4.y = (1.f - wy) * wx * vy0 * vx1 * mask;
    wv4.z = wy * (1.f - wx) * vy1 * vx0 * mask;
    wv4.w = wy * wx * vy1 * vx1 * mask;
    uint4 ov;
    ov.x = (unsigned)(((y0c << 6) + x0c) << 8);
    ov.y = (unsigned)(((y0c << 6) + x1c) << 8);
    ov.z = (unsigned)(((y1c << 6) + x0c) << 8);
    ov.w = (unsigned)(((y1c << 6) + x1c) << 8);

    float* p = SW + (size_t)(k * 16384 + bhw) * 8;
    *(float4*)p = wv4;
    *(uint4*)(p + 4) = ov;
  }
}

// ---------------------------------------------------------------------------
// Kernel 5: fused sample + main GEMM, DEPTH-2 pipeline, 512 thr, grid 512.
//  BM=256 x BN=32 -> 2 independent blocks/CU (16 waves/CU, 4/SIMD).
//  8 waves: wm = wv (32-row m-stripe each), acc[2][2], aF[2], bF[2].
//  Sampling role: waves 0-3 only (t<256): 32 rows x 8 ch-quads.
//  Raw s_barrier + lgkmcnt-only wait; gathers/aF for kt+2 in flight across it.
// ---------------------------------------------------------------------------
#define FSTEP(KT, Q, AF, BUF, DOSW)                                            \
  do {                                                                         \
    if (t < 256) {                                                             \
      float s0_ = wv4.x * bf2f(Q[0].x) + wv4.y * bf2f(Q[1].x) +                \
                  wv4.z * bf2f(Q[2].x) + wv4.w * bf2f(Q[3].x);                 \
      float s1_ = wv4.x * bf2f(Q[0].y) + wv4.y * bf2f(Q[1].y) +                \
                  wv4.z * bf2f(Q[2].y) + wv4.w * bf2f(Q[3].y);                 \
      float s2_ = wv4.x * bf2f(Q[0].z) + wv4.y * bf2f(Q[1].z) +                \
                  wv4.z * bf2f(Q[2].z) + wv4.w * bf2f(Q[3].z);                 \
      float s3_ = wv4.x * bf2f(Q[0].w) + wv4.y * bf2f(Q[1].w) +                \
                  wv4.z * bf2f(Q[2].w) + wv4.w * bf2f(Q[3].w);                 \
      union { __hip_bfloat162 h2[2]; ushort4 v; } pk_;                         \
      pk_.h2[0] = __float22bfloat162_rn(make_float2(s0_, s1_));                \
      pk_.h2[1] = __float22bfloat162_rn(make_float2(s2_, s3_));                \
      *(ushort4*)(&Bs[BUF][bsw]) = pk_.v;                                      \
      if (DOSW && ((KT) & 7) == 0 && (KT) < 64) {                              \
        const float* swp_ =                                                    \
            SW + ((size_t)(((((KT) >> 3) + 1) << 14) + n0 + r)) * 8;           \
        wv4n = *(const float4*)swp_;                                           \
        ovn  = *(const uint4*)(swp_ + 4);                                      \
      }                                                                        \
      if ((KT) < 70) {                                                         \
        int kn_ = (KT) + 2;                                                    \
        uint4 o_ = (((KT) & 7) >= 6) ? ovn : ov;                               \
        unsigned c_ = (unsigned)(((kn_ & 7) << 5) + ch0);                      \
        Q[0] = *(const ushort4*)(xb + o_.x + c_);                              \
        Q[1] = *(const ushort4*)(xb + o_.y + c_);                              \
        Q[2] = *(const ushort4*)(xb + o_.z + c_);                              \
        Q[3] = *(const ushort4*)(xb + o_.w + c_);                              \
      }                                                                        \
    }                                                                          \
    asm volatile("s_waitcnt lgkmcnt(0)\n\ts_barrier" ::: "memory");            \
    bf16x8 bF0_ = *(const bf16x8*)(&Bs[BUF][((lane & 15)) * 40 +               \
                                            (lane >> 4) * 8]);                 \
    bf16x8 bF1_ = *(const bf16x8*)(&Bs[BUF][(16 + (lane & 15)) * 40 +          \
                                            (lane >> 4) * 8]);                 \
    _Pragma("unroll")                                                          \
    for (int i_ = 0; i_ < 2; ++i_) {                                           \
      acc[i_][0] =                                                             \
          __builtin_amdgcn_mfma_f32_16x16x32_bf16(AF[i_], bF0_, acc[i_][0],    \
                                                  0, 0, 0);                    \
      acc[i_][1] =                                                             \
          __builtin_amdgcn_mfma_f32_16x16x32_bf16(AF[i_], bF1_, acc[i_][1],    \
                                                  0, 0, 0);                    \
    }                                                                          \
    if ((KT) < 70) {                                                           \
      int kn_ = (KT) + 2;                                                      \
      _Pragma("unroll")                                                        \
      for (int i_ = 0; i_ < 2; ++i_)                                           \
        AF[i_] = *(const bf16x8*)(wpBase + ((size_t)(kn_ * 16 + i_)) * 512);   \
    }                                                                          \
  } while (0)

__global__ __launch_bounds__(512, 4) void k_fused(const unsigned short* __restrict__ Wpk,
                                                  const unsigned short* __restrict__ xTb,
                                                  const float* __restrict__ SW,
                                                  float* __restrict__ out) {
  __shared__ __align__(16) unsigned short Bs[2][32 * 40];  // 5 KB
  int t = threadIdx.x;
  int wv = t >> 6, lane = t & 63;
  int wm = wv;                                    // 8 m-stripes of 32 rows
  int bid = (int)blockIdx.x;
  // XCD-contiguous: 512 blocks = 8 XCDs x 64 chunks of 32 n-positions
  int n0 = ((bid & 7) * 64 + (bid >> 3)) * 32;
  int b  = n0 >> 12;
  const unsigned short* xb = xTb + ((size_t)b << 20);

  // sampling role (waves 0-3): row r (0..31), channel quad g (0..7)
  int r = (t & 255) >> 3, g = t & 7;
  int ch0 = g * 4;
  int bsw = r * 40 + ch0;

  // A-fragment base: wave covers m-blocks 2*wm, 2*wm+1
  const unsigned short* wpBase = Wpk + (size_t)(wm * 2) * 512 + (size_t)lane * 8;

  f32x4 acc[2][2] = {};

  float4 wv4 = {}, wv4n = {};
  uint4 ov = {}, ovn = {};
  ushort4 qA[4] = {}, qB[4] = {};
  bf16x8 aFA[2], aFB[2];

  // prologue
  if (t < 256) {
    const float* sw = SW + ((size_t)(n0 + r)) * 8;
    wv4 = *(const float4*)sw;
    ov  = *(const uint4*)(sw + 4);
    wv4n = wv4; ovn = ov;
    unsigned c0_ = (unsigned)ch0;
    qA[0] = *(const ushort4*)(xb + ov.x + c0_);
    qA[1] = *(const ushort4*)(xb + ov.y + c0_);
    qA[2] = *(const ushort4*)(xb + ov.z + c0_);
    qA[3] = *(const ushort4*)(xb + ov.w + c0_);
    unsigned c1_ = (unsigned)(32 + ch0);
    qB[0] = *(const ushort4*)(xb + ov.x + c1_);
    qB[1] = *(const ushort4*)(xb + ov.y + c1_);
    qB[2] = *(const ushort4*)(xb + ov.z + c1_);
    qB[3] = *(const ushort4*)(xb + ov.w + c1_);
  }
#pragma unroll
  for (int i = 0; i < 2; ++i) {
    aFA[i] = *(const bf16x8*)(wpBase + (size_t)i * 512);
    aFB[i] = *(const bf16x8*)(wpBase + (size_t)(16 + i) * 512);
  }

  for (int kt = 0; kt < 72; kt += 2) {
    FSTEP(kt,     qA, aFA, 0, 1);
    FSTEP(kt + 1, qB, aFB, 1, 0);
    if (t < 256 && (kt & 7) == 6) { wv4 = wv4n; ov = ovn; }
  }

  // epilogue: wave wm rows [wm*32, wm*32+32), cols n0..n0+31
  int quad = lane >> 4, cl = lane & 15;
  float* ob = out + (((size_t)b) << 20);
#pragma unroll
  for (int i = 0; i < 2; ++i) {
    int mbase = wm * 32 + i * 16 + quad * 4;
#pragma unroll
    for (int j = 0; j < 2; ++j) {
      int hw = (n0 & 4095) + j * 16 + cl;
      float* op = ob + hw;
#pragma unroll
      for (int rr = 0; rr < 4; ++rr)
        op[((size_t)(mbase + rr)) << 12] = acc[i][j][rr];
    }
  }
}

// ---------------------------------------------------------------------------
extern "C" void kernel_launch(void* const* d_in, const int* in_sizes, int n_in,
                              void* d_out, int out_size, void* d_ws, size_t ws_size,
                              hipStream_t stream) {
  const float* x        = (const float*)d_in[0];
  const float* offset_w = (const float*)d_in[1];
  const float* offset_b = (const float*)d_in[2];
  const float* dcn_w    = (const float*)d_in[3];
  float* out = (float*)d_out;

  char* ws = (char*)d_ws;
  size_t off = 0;
  auto carve = [&](size_t bytes) -> void* {
    void* p = ws + off;
    off += (bytes + 255) & ~(size_t)255;
    return p;
  };
  unsigned short* xTb = (unsigned short*)carve(4ull * 64 * 64 * 256 * 2);   // 8 MB
  unsigned short* Wpk = (unsigned short*)carve(72ull * 8192 * 2);           // 1.125 MB
  unsigned short* Wob = (unsigned short*)carve(32ull * KDIM * 2);           // 144 KB
  unsigned short* zp  = (unsigned short*)carve(256);                        // zero page
  float*          O2p = (float*)carve(2ull * 16384 * 32 * 4);               // 4 MB
  float*          SW  = (float*)carve(9ull * 16384 * 8 * 4);                // 4.5 MB
  (void)ws_size; (void)in_sizes; (void)n_in; (void)out_size;

  k_transpose<<<dim3(128, 8, 4), 256, 0, stream>>>(x, xTb);
  k_wprep<<<dim3((72 * 8192 + 32 * KDIM + 128 + 255) / 256), 256, 0, stream>>>(
      dcn_w, offset_w, Wpk, Wob, zp);
  k_offs_gemm<<<dim3(256, 2), 256, 0, stream>>>(xTb, Wob, zp, O2p);
  k_sweights<<<dim3(512), 256, 0, stream>>>(O2p, offset_b, SW);
  k_fused<<<dim3(512), 512, 0, stream>>>(Wpk, xTb, SW, out);
}

// Round 4
// 147.759 us; speedup vs baseline: 1.0566x; 1.0122x over previous
//
#include <hip/hip_runtime.h>
#include <hip/hip_bf16.h>
#include <stdint.h>
#include <math.h>

#define KDIM 2304   // 9 * 256

typedef __attribute__((ext_vector_type(8))) short bf16x8;
typedef __attribute__((ext_vector_type(4))) float f32x4;

__device__ inline unsigned short f2bf(float f) {
  union { float f; unsigned int u; } v; v.f = f;
  unsigned int u = v.u;
  unsigned int r = (u + 0x7FFFu + ((u >> 16) & 1u)) >> 16;
  return (unsigned short)r;
}
__device__ inline float bf2f(unsigned short h) {
  union { unsigned int u; float f; } v; v.u = ((unsigned int)h) << 16;
  return v.f;
}

__device__ inline void gl2lds16(const void* g, void* l) {
  __builtin_amdgcn_global_load_lds((const __attribute__((address_space(1))) void*)g,
                                   (__attribute__((address_space(3))) void*)l,
                                   16, 0, 0);
}

// ---------------------------------------------------------------------------
// Kernel 1: fused prep.
//  blocks [0, 4096):    x (B,C,H,W) fp32 -> xTb (B,H,W,C) bf16
//  blocks [4096, 6689): weight prep (Wpk A-frag order; Wob; zero page)
// ---------------------------------------------------------------------------
__global__ __launch_bounds__(256) void k_prep(const float* __restrict__ x,
                                              unsigned short* __restrict__ xTb,
                                              const float* __restrict__ dcn_w,
                                              const float* __restrict__ offset_w,
                                              unsigned short* __restrict__ Wpk,
                                              unsigned short* __restrict__ Wob,
                                              unsigned short* __restrict__ zp) {
  __shared__ float tile[32][33];
  int bx = (int)blockIdx.x;
  int t = threadIdx.x;
  if (bx < 4096) {
    int tx = t & 31, ty = t >> 5;
    int p0 = (bx & 127) * 32;
    int c0 = ((bx >> 7) & 7) * 32;
    int b  = bx >> 10;
    const float* xb = x + ((size_t)b << 20);
#pragma unroll
    for (int i = 0; i < 4; ++i) {
      int c = c0 + ty + i * 8;
      tile[ty + i * 8][tx] = xb[((size_t)c << 12) + p0 + tx];
    }
    __syncthreads();
    unsigned short* ob = xTb + ((size_t)b << 20);
#pragma unroll
    for (int i = 0; i < 4; ++i) {
      int p = p0 + ty + i * 8;
      ob[(((size_t)p) << 8) + c0 + tx] = f2bf(tile[tx][ty + i * 8]);
    }
  } else {
    int gid = (bx - 4096) * 256 + t;
    const int N1 = 72 * 8192;
    const int N2 = 32 * KDIM;
    if (gid < N1) {
      int j = gid & 7;
      int lane = (gid >> 3) & 63;
      int mb = (gid >> 9) & 15;
      int kc = gid >> 13;
      int row = mb * 16 + (lane & 15);
      int gk = kc * 32 + ((lane >> 4) << 3) + j;
      int c = gk & 255, kidx = gk >> 8;
      Wpk[gid] = f2bf(dcn_w[((size_t)(row * 256 + c)) * 9 + kidx]);
    } else if (gid < N1 + N2) {
      int g = gid - N1;
      int ch = g / KDIM, k = g % KDIM;
      int kidx = k >> 8, c = k & 255;
      Wob[g] = (ch < 27) ? f2bf(offset_w[((size_t)(ch * 256 + c)) * 9 + kidx])
                         : (unsigned short)0;
    } else if (gid < N1 + N2 + 128) {
      zp[gid - N1 - N2] = 0;
    }
  }
}

// ---------------------------------------------------------------------------
// Kernel 2: offset conv GEMM (full K) + fused sampling-table epilogue.
//  Grid 256 (XCD swizzle), 512 thr / 8 waves. 64 bhw rows x 32 cols, 72 K-steps.
//  Wave w computes one 16x16 fragment: m-frag = w&3, n-frag = w>>2.
//  Staging roles: waves 0-3 stage A (64x32), waves 4-5 stage B (32x32).
//  Counted vmcnt + raw s_barrier (next stage stays in flight).
//  Epilogue: acc -> LDS Os -> bias + sigmoid + bilinear table -> SW.
//  Eliminates the O2p roundtrip and the separate k_sweights kernel.
// ---------------------------------------------------------------------------
__global__ __launch_bounds__(512) void k_offs(const unsigned short* __restrict__ xTb,
                                              const unsigned short* __restrict__ Wob,
                                              const unsigned short* __restrict__ zp,
                                              const float* __restrict__ offb,
                                              float* __restrict__ SW) {
  __shared__ unsigned short As[2][64 * 32];  // 8 KB
  __shared__ unsigned short Bs[2][32 * 32];  // 4 KB
  __shared__ float Os[64][33];               // 8.25 KB
  int t = threadIdx.x;
  int wv = t >> 6, lane = t & 63;
  int bid = (int)blockIdx.x;
  int swz = (bid & 7) * 32 + (bid >> 3);     // same swizzle as k_fused
  int n0 = swz * 64;
  int r0 = t >> 2, coff = (t & 3) * 8;       // A-stage mapping (t < 256)

  int rowA = n0 + (r0 & 63);
  int b_ = rowA >> 12, hw = rowA & 4095, h = hw >> 6, w = hw & 63;

  f32x4 acc = {};

  auto stage = [&](int kt, int buf) {
    int k0 = kt * 32;
    int kidx = k0 >> 8, c0 = k0 & 255;
    if (t < 256) {
      int di = kidx / 3 - 1, dj = kidx % 3 - 1;
      int y = h + di, xx = w + dj;
      const unsigned short* g = (y >= 0 && y < 64 && xx >= 0 && xx < 64)
          ? xTb + (((((size_t)b_) << 12) + (y << 6) + xx) << 8) + c0 + coff
          : zp;
      gl2lds16(g, (char*)As[buf] + wv * 1024);
    } else if (t < 384) {
      int tt = t - 256;  // 0..127: 32 rows x 4 lanes of 16B
      const unsigned short* gB = Wob + (size_t)(tt >> 2) * KDIM + k0 + (tt & 3) * 8;
      gl2lds16(gB, (char*)Bs[buf] + (wv - 4) * 1024);
    }
  };

  stage(0, 0);

  int mf = wv & 3, nf = wv >> 2;
  for (int kt = 0; kt < 72; ++kt) {
    int buf = kt & 1;
    if (kt + 1 < 72) {
      stage(kt + 1, buf ^ 1);
      if (t < 384) asm volatile("s_waitcnt vmcnt(1)" ::: "memory");
      else         asm volatile("s_waitcnt vmcnt(0)" ::: "memory");
    } else {
      asm volatile("s_waitcnt vmcnt(0)" ::: "memory");
    }
    asm volatile("s_barrier" ::: "memory");

    bf16x8 aF = *(const bf16x8*)(As[buf] + (mf * 16 + (lane & 15)) * 32 + (lane >> 4) * 8);
    bf16x8 bF = *(const bf16x8*)(Bs[buf] + (nf * 16 + (lane & 15)) * 32 + (lane >> 4) * 8);
    acc = __builtin_amdgcn_mfma_f32_16x16x32_bf16(aF, bF, acc, 0, 0, 0);

    asm volatile("s_barrier" ::: "memory");
  }

  // epilogue: fragment -> Os
  int quad = lane >> 4, cl = lane & 15;
#pragma unroll
  for (int r = 0; r < 4; ++r)
    Os[mf * 16 + quad * 4 + r][nf * 16 + cl] = acc[r];
  __syncthreads();

  // 576 items = 9 k x 64 rows; k-major so SW writes coalesce per k.
  for (int item = t; item < 576; item += 512) {
    int bl = item & 63, k = item >> 6;
    int bhw = n0 + bl;
    int h_ = (bhw >> 6) & 63, w_ = bhw & 63;
    float dy = Os[bl][2 * k]     + offb[2 * k];
    float dx = Os[bl][2 * k + 1] + offb[2 * k + 1];
    float mv = Os[bl][18 + k]    + offb[18 + k];
    float mask = 1.0f / (1.0f + expf(-mv));

    float py = (float)(h_ - 1 + k / 3) + dy;
    float px = (float)(w_ - 1 + k % 3) + dx;
    float y0f = floorf(py), x0f = floorf(px);
    float wy = py - y0f, wx = px - x0f;
    int y0 = (int)y0f, x0 = (int)x0f;
    int y1 = y0 + 1, x1 = x0 + 1;

    float vy0 = (y0 >= 0 && y0 < 64) ? 1.f : 0.f;
    float vy1 = (y1 >= 0 && y1 < 64) ? 1.f : 0.f;
    float vx0 = (x0 >= 0 && x0 < 64) ? 1.f : 0.f;
    float vx1 = (x1 >= 0 && x1 < 64) ? 1.f : 0.f;
    int y0c = min(max(y0, 0), 63), y1c = min(max(y1, 0), 63);
    int x0c = min(max(x0, 0), 63), x1c = min(max(x1, 0), 63);

    float4 wv4;
    wv4.x = (1.f - wy) * (1.f - wx) * vy0 * vx0 * mask;
    wv4.y = (1.f - wy) * wx * vy0 * vx1 * mask;
    wv4.z = wy * (1.f - wx) * vy1 * vx0 * mask;
    wv4.w = wy * wx * vy1 * vx1 * mask;
    uint4 ov;
    ov.x = (unsigned)(((y0c << 6) + x0c) << 8);
    ov.y = (unsigned)(((y0c << 6) + x1c) << 8);
    ov.z = (unsigned)(((y1c << 6) + x0c) << 8);
    ov.w = (unsigned)(((y1c << 6) + x1c) << 8);

    float* p = SW + (size_t)(k * 16384 + bhw) * 8;
    *(float4*)p = wv4;
    *(uint4*)(p + 4) = ov;
  }
}

// ---------------------------------------------------------------------------
// Kernel 3: fused sample + main GEMM, DEPTH-2 pipeline (round-2 best: 51.4us).
//  BM=256 x BN=64, BK=32, grid 256, XCD-swizzled blocks, 512 thr / 8 waves.
//  Gathers + A-fragments for kt+2 issued at kt; loads span two raw
//  s_barriers (lgkmcnt-only wait, no vmcnt drain).
// ---------------------------------------------------------------------------
#define FSTEP(KT, Q, AF, BUF, DOSW)                                            \
  do {                                                                         \
    float s0_ = wv4.x * bf2f(Q[0].x) + wv4.y * bf2f(Q[1].x) +                  \
                wv4.z * bf2f(Q[2].x) + wv4.w * bf2f(Q[3].x);                   \
    float s1_ = wv4.x * bf2f(Q[0].y) + wv4.y * bf2f(Q[1].y) +                  \
                wv4.z * bf2f(Q[2].y) + wv4.w * bf2f(Q[3].y);                   \
    float s2_ = wv4.x * bf2f(Q[0].z) + wv4.y * bf2f(Q[1].z) +                  \
                wv4.z * bf2f(Q[2].z) + wv4.w * bf2f(Q[3].z);                   \
    float s3_ = wv4.x * bf2f(Q[0].w) + wv4.y * bf2f(Q[1].w) +                  \
                wv4.z * bf2f(Q[2].w) + wv4.w * bf2f(Q[3].w);                   \
    union { __hip_bfloat162 h2[2]; ushort4 v; } pk_;                           \
    pk_.h2[0] = __float22bfloat162_rn(make_float2(s0_, s1_));                  \
    pk_.h2[1] = __float22bfloat162_rn(make_float2(s2_, s3_));                  \
    *(ushort4*)(&Bs[BUF][bsw]) = pk_.v;                                        \
    if (DOSW && ((KT) & 7) == 0 && (KT) < 64) {                                \
      const float* swp_ =                                                      \
          SW + ((size_t)(((((KT) >> 3) + 1) << 14) + n0 + r)) * 8;             \
      wv4n = *(const float4*)swp_;                                             \
      ovn  = *(const uint4*)(swp_ + 4);                                        \
    }                                                                          \
    if ((KT) < 70) {                                                           \
      int kn_ = (KT) + 2;                                                      \
      uint4 o_ = (((KT) & 7) >= 6) ? ovn : ov;                                 \
      unsigned c_ = (unsigned)(((kn_ & 7) << 5) + ch0);                        \
      Q[0] = *(const ushort4*)(xb + o_.x + c_);                                \
      Q[1] = *(const ushort4*)(xb + o_.y + c_);                                \
      Q[2] = *(const ushort4*)(xb + o_.z + c_);                                \
      Q[3] = *(const ushort4*)(xb + o_.w + c_);                                \
    }                                                                          \
    asm volatile("s_waitcnt lgkmcnt(0)\n\ts_barrier" ::: "memory");            \
    bf16x8 bF0_ = *(const bf16x8*)(&Bs[BUF][(wn * 32 + (lane & 15)) * 40 +     \
                                            (lane >> 4) * 8]);                 \
    bf16x8 bF1_ = *(const bf16x8*)(&Bs[BUF][(wn * 32 + 16 + (lane & 15)) * 40 +\
                                            (lane >> 4) * 8]);                 \
    _Pragma("unroll")                                                          \
    for (int i_ = 0; i_ < 4; ++i_) {                                           \
      acc[i_][0] =                                                             \
          __builtin_amdgcn_mfma_f32_16x16x32_bf16(AF[i_], bF0_, acc[i_][0],    \
                                                  0, 0, 0);                    \
      acc[i_][1] =                                                             \
          __builtin_amdgcn_mfma_f32_16x16x32_bf16(AF[i_], bF1_, acc[i_][1],    \
                                                  0, 0, 0);                    \
    }                                                                          \
    if ((KT) < 70) {                                                           \
      int kn_ = (KT) + 2;                                                      \
      _Pragma("unroll")                                                        \
      for (int i_ = 0; i_ < 4; ++i_)                                           \
        AF[i_] = *(const bf16x8*)(wpBase + ((size_t)kn_ * 16 + i_) * 512);     \
    }                                                                          \
  } while (0)

__global__ __launch_bounds__(512) void k_fused(const unsigned short* __restrict__ Wpk,
                                               const unsigned short* __restrict__ xTb,
                                               const float* __restrict__ SW,
                                               float* __restrict__ out) {
  __shared__ __align__(16) unsigned short Bs[2][64 * 40];  // 10 KB
  int t = threadIdx.x;
  int wv = t >> 6, lane = t & 63;
  int wm = wv & 3, wn = wv >> 2;
  int bid = (int)blockIdx.x;
  int swz = (bid & 7) * 32 + (bid >> 3);   // XCD-contiguous chunks (256 = 8*32)
  int n0 = swz * 64;
  int b  = n0 >> 12;
  const unsigned short* xb = xTb + ((size_t)b << 20);

  // sampling role: row r (0..63), channel quad g (0..7) -> ch = g*4
  int r = t >> 3, g = t & 7;
  int ch0 = g * 4;
  int bsw = r * 40 + ch0;

  // A-fragment base: wave covers m-blocks wm*4 .. wm*4+3
  const unsigned short* wpBase = Wpk + ((size_t)(wm * 4 * 64 + lane)) * 8;

  f32x4 acc[4][2] = {};

  float4 wv4, wv4n; uint4 ov, ovn;
  {
    const float* sw = SW + ((size_t)(n0 + r)) * 8;
    wv4 = *(const float4*)sw;
    ov  = *(const uint4*)(sw + 4);
  }
  wv4n = wv4; ovn = ov;

  ushort4 qA[4], qB[4];
  bf16x8 aFA[4], aFB[4];

  // prologue: gathers for kt=0 (qA) and kt=1 (qB); A-fragments for kt=0,1
  {
    unsigned c0_ = (unsigned)ch0;
    qA[0] = *(const ushort4*)(xb + ov.x + c0_);
    qA[1] = *(const ushort4*)(xb + ov.y + c0_);
    qA[2] = *(const ushort4*)(xb + ov.z + c0_);
    qA[3] = *(const ushort4*)(xb + ov.w + c0_);
    unsigned c1_ = (unsigned)(32 + ch0);
    qB[0] = *(const ushort4*)(xb + ov.x + c1_);
    qB[1] = *(const ushort4*)(xb + ov.y + c1_);
    qB[2] = *(const ushort4*)(xb + ov.z + c1_);
    qB[3] = *(const ushort4*)(xb + ov.w + c1_);
#pragma unroll
    for (int i = 0; i < 4; ++i) {
      aFA[i] = *(const bf16x8*)(wpBase + (size_t)i * 512);
      aFB[i] = *(const bf16x8*)(wpBase + (size_t)(16 + i) * 512);
    }
  }

  for (int kt = 0; kt < 72; kt += 2) {
    FSTEP(kt,     qA, aFA, 0, 1);
    FSTEP(kt + 1, qB, aFB, 1, 0);
    if ((kt & 7) == 6) { wv4 = wv4n; ov = ovn; }  // rotate after group end
  }

  // epilogue
  int quad = lane >> 4, cl = lane & 15;
  float* ob = out + (((size_t)b) << 20);
#pragma unroll
  for (int i = 0; i < 4; ++i) {
    int mbase = wm * 64 + i * 16 + quad * 4;
#pragma unroll
    for (int j = 0; j < 2; ++j) {
      int hw = (n0 & 4095) + wn * 32 + j * 16 + cl;
      float* op = ob + hw;
#pragma unroll
      for (int rr = 0; rr < 4; ++rr)
        op[((size_t)(mbase + rr)) << 12] = acc[i][j][rr];
    }
  }
}

// ---------------------------------------------------------------------------
extern "C" void kernel_launch(void* const* d_in, const int* in_sizes, int n_in,
                              void* d_out, int out_size, void* d_ws, size_t ws_size,
                              hipStream_t stream) {
  const float* x        = (const float*)d_in[0];
  const float* offset_w = (const float*)d_in[1];
  const float* offset_b = (const float*)d_in[2];
  const float* dcn_w    = (const float*)d_in[3];
  float* out = (float*)d_out;

  char* ws = (char*)d_ws;
  size_t off = 0;
  auto carve = [&](size_t bytes) -> void* {
    void* p = ws + off;
    off += (bytes + 255) & ~(size_t)255;
    return p;
  };
  unsigned short* xTb = (unsigned short*)carve(4ull * 64 * 64 * 256 * 2);   // 8 MB
  unsigned short* Wpk = (unsigned short*)carve(72ull * 8192 * 2);           // 1.125 MB
  unsigned short* Wob = (unsigned short*)carve(32ull * KDIM * 2);           // 144 KB
  unsigned short* zp  = (unsigned short*)carve(256);                        // zero page
  float*          SW  = (float*)carve(9ull * 16384 * 8 * 4);                // 4.5 MB
  (void)ws_size; (void)in_sizes; (void)n_in; (void)out_size;

  // prep grid: 4096 transpose blocks + ceil((72*8192 + 32*KDIM + 128)/256)
  const int WPREP_BLOCKS = (72 * 8192 + 32 * KDIM + 128 + 255) / 256;
  k_prep<<<dim3(4096 + WPREP_BLOCKS), 256, 0, stream>>>(
      x, xTb, dcn_w, offset_w, Wpk, Wob, zp);
  k_offs<<<dim3(256), 512, 0, stream>>>(xTb, Wob, zp, offset_b, SW);
  k_fused<<<dim3(256), 512, 0, stream>>>(Wpk, xTb, SW, out);
}

// Round 5
// 142.892 us; speedup vs baseline: 1.0925x; 1.0341x over previous
//
#include <hip/hip_runtime.h>
#include <hip/hip_bf16.h>
#include <stdint.h>
#include <math.h>

#define KDIM 2304   // 9 * 256

typedef __attribute__((ext_vector_type(8))) short bf16x8;
typedef __attribute__((ext_vector_type(4))) float f32x4;

__device__ inline unsigned short f2bf(float f) {
  union { float f; unsigned int u; } v; v.f = f;
  unsigned int u = v.u;
  unsigned int r = (u + 0x7FFFu + ((u >> 16) & 1u)) >> 16;
  return (unsigned short)r;
}
__device__ inline float bf2f(unsigned short h) {
  union { unsigned int u; float f; } v; v.u = ((unsigned int)h) << 16;
  return v.f;
}

__device__ inline void gl2lds16(const void* g, void* l) {
  __builtin_amdgcn_global_load_lds((const __attribute__((address_space(1))) void*)g,
                                   (__attribute__((address_space(3))) void*)l,
                                   16, 0, 0);
}

// ---------------------------------------------------------------------------
// Kernel 1: fused prep.
//  blocks [0, 2048):    x (B,C,H,W) fp32 -> xTb (B,H,W,C) bf16
//    tile = 32 positions x 64 channels; float4 reads, ushort4 writes,
//    both sides 128B-contiguous per lane group.
//  blocks [2048, ...):  weight prep (Wpk A-frag order; Wob; zero page)
// ---------------------------------------------------------------------------
__global__ __launch_bounds__(256) void k_prep(const float* __restrict__ x,
                                              unsigned short* __restrict__ xTb,
                                              const float* __restrict__ dcn_w,
                                              const float* __restrict__ offset_w,
                                              unsigned short* __restrict__ Wpk,
                                              unsigned short* __restrict__ Wob,
                                              unsigned short* __restrict__ zp) {
  __shared__ float tile[32][65];
  int bx = (int)blockIdx.x;
  int t = threadIdx.x;
  if (bx < 2048) {
    int pt = bx & 127, ct = (bx >> 7) & 3, b = bx >> 9;
    int p0 = pt * 32, c0 = ct * 64;
    const float* xb = x + ((size_t)b << 20);
#pragma unroll
    for (int i = 0; i < 2; ++i) {
      int idx = t + i * 256;            // [0,512)
      int c = idx >> 3, pq = idx & 7;   // c 0..63, pq 0..7
      float4 v = *(const float4*)(xb + ((size_t)(c0 + c) << 12) + p0 + pq * 4);
      tile[pq * 4 + 0][c] = v.x;
      tile[pq * 4 + 1][c] = v.y;
      tile[pq * 4 + 2][c] = v.z;
      tile[pq * 4 + 3][c] = v.w;
    }
    __syncthreads();
    unsigned short* ob = xTb + ((size_t)b << 20);
#pragma unroll
    for (int i = 0; i < 2; ++i) {
      int idx = t + i * 256;            // [0,512)
      int p = idx >> 4, cg = idx & 15;  // p 0..31, cg 0..15
      ushort4 o;
      o.x = f2bf(tile[p][cg * 4 + 0]);
      o.y = f2bf(tile[p][cg * 4 + 1]);
      o.z = f2bf(tile[p][cg * 4 + 2]);
      o.w = f2bf(tile[p][cg * 4 + 3]);
      *(ushort4*)(ob + (((size_t)(p0 + p)) << 8) + c0 + cg * 4) = o;
    }
  } else {
    int gid = (bx - 2048) * 256 + t;
    const int N1 = 72 * 8192;
    const int N2 = 32 * KDIM;
    if (gid < N1) {
      int j = gid & 7;
      int lane = (gid >> 3) & 63;
      int mb = (gid >> 9) & 15;
      int kc = gid >> 13;
      int row = mb * 16 + (lane & 15);
      int gk = kc * 32 + ((lane >> 4) << 3) + j;
      int c = gk & 255, kidx = gk >> 8;
      Wpk[gid] = f2bf(dcn_w[((size_t)(row * 256 + c)) * 9 + kidx]);
    } else if (gid < N1 + N2) {
      int g = gid - N1;
      int ch = g / KDIM, k = g % KDIM;
      int kidx = k >> 8, c = k & 255;
      Wob[g] = (ch < 27) ? f2bf(offset_w[((size_t)(ch * 256 + c)) * 9 + kidx])
                         : (unsigned short)0;
    } else if (gid < N1 + N2 + 128) {
      zp[gid - N1 - N2] = 0;
    }
  }
}

// ---------------------------------------------------------------------------
// Kernel 2: offset conv GEMM + fused sampling-table epilogue.
//  Grid 512 (XCD swizzle, 2 blocks/CU), 256 thr / 4 waves.
//  Tile: 32 bhw rows x 32 cols, 72 K-steps of BK=32.
//  DEPTH-3 pipeline: 4 LDS buffers, stages kt+1..kt+3 in flight, uniform
//  vmcnt(2)/thread (every thread issues exactly 1 gl2lds per stage),
//  ONE raw s_barrier per iteration (stage issued after it overwrites the
//  buffer last read before that same barrier -> race-free with 4 buffers).
// ---------------------------------------------------------------------------
__global__ __launch_bounds__(256) void k_offs(const unsigned short* __restrict__ xTb,
                                              const unsigned short* __restrict__ Wob,
                                              const unsigned short* __restrict__ zp,
                                              const float* __restrict__ offb,
                                              float* __restrict__ SW) {
  __shared__ unsigned short As[4][32 * 32];  // 8 KB
  __shared__ unsigned short Bs[4][32 * 32];  // 8 KB
  __shared__ float Os[32][33];               // 4.2 KB
  int t = threadIdx.x;
  int wv = t >> 6, lane = t & 63;
  int bid = (int)blockIdx.x;
  int swz = (bid & 7) * 64 + (bid >> 3);     // 512 = 8 XCDs x 64 chunks
  int n0 = swz * 32;

  // A-stage role (t<128): row r0 (0..31), 16B chunk (t&3)
  int r0 = (t >> 2) & 31, coff = (t & 3) * 8;
  int rowA = n0 + r0;
  int b_ = rowA >> 12, hw = rowA & 4095, h = hw >> 6, w = hw & 63;
  // B-stage role (t>=128): row rB (0..31), 16B chunk
  int rB = ((t - 128) >> 2) & 31;

  f32x4 acc = {};

  auto stage = [&](int kt) {
    int buf = kt & 3;
    int k0 = kt * 32;
    int kidx = k0 >> 8, c0 = k0 & 255;
    if (t < 128) {
      int di = kidx / 3 - 1, dj = kidx % 3 - 1;
      int y = h + di, xx = w + dj;
      const unsigned short* g = (y >= 0 && y < 64 && xx >= 0 && xx < 64)
          ? xTb + (((((size_t)b_) << 12) + (y << 6) + xx) << 8) + c0 + coff
          : zp;
      gl2lds16(g, (char*)As[buf] + wv * 1024);
    } else {
      const unsigned short* gB = Wob + (size_t)rB * KDIM + k0 + coff;
      gl2lds16(gB, (char*)Bs[buf] + (wv - 2) * 1024);
    }
  };

  stage(0); stage(1); stage(2);

  int mf = wv & 1, nf = wv >> 1;
  for (int kt = 0; kt < 72; ++kt) {
    if (kt <= 69)      asm volatile("s_waitcnt vmcnt(2)" ::: "memory");
    else if (kt == 70) asm volatile("s_waitcnt vmcnt(1)" ::: "memory");
    else               asm volatile("s_waitcnt vmcnt(0)" ::: "memory");
    asm volatile("s_barrier" ::: "memory");
    if (kt + 3 < 72) stage(kt + 3);
    int buf = kt & 3;
    bf16x8 aF = *(const bf16x8*)(As[buf] + (mf * 16 + (lane & 15)) * 32 + (lane >> 4) * 8);
    bf16x8 bF = *(const bf16x8*)(Bs[buf] + (nf * 16 + (lane & 15)) * 32 + (lane >> 4) * 8);
    acc = __builtin_amdgcn_mfma_f32_16x16x32_bf16(aF, bF, acc, 0, 0, 0);
  }

  // epilogue: fragment -> Os
  int quad = lane >> 4, cl = lane & 15;
#pragma unroll
  for (int r = 0; r < 4; ++r)
    Os[mf * 16 + quad * 4 + r][nf * 16 + cl] = acc[r];
  __syncthreads();

  // 288 items = 9 k x 32 rows; k-major so SW writes coalesce per k.
  for (int item = t; item < 288; item += 256) {
    int bl = item & 31, k = item >> 5;
    int bhw = n0 + bl;
    int h_ = (bhw >> 6) & 63, w_ = bhw & 63;
    float dy = Os[bl][2 * k]     + offb[2 * k];
    float dx = Os[bl][2 * k + 1] + offb[2 * k + 1];
    float mv = Os[bl][18 + k]    + offb[18 + k];
    float mask = 1.0f / (1.0f + expf(-mv));

    float py = (float)(h_ - 1 + k / 3) + dy;
    float px = (float)(w_ - 1 + k % 3) + dx;
    float y0f = floorf(py), x0f = floorf(px);
    float wy = py - y0f, wx = px - x0f;
    int y0 = (int)y0f, x0 = (int)x0f;
    int y1 = y0 + 1, x1 = x0 + 1;

    float vy0 = (y0 >= 0 && y0 < 64) ? 1.f : 0.f;
    float vy1 = (y1 >= 0 && y1 < 64) ? 1.f : 0.f;
    float vx0 = (x0 >= 0 && x0 < 64) ? 1.f : 0.f;
    float vx1 = (x1 >= 0 && x1 < 64) ? 1.f : 0.f;
    int y0c = min(max(y0, 0), 63), y1c = min(max(y1, 0), 63);
    int x0c = min(max(x0, 0), 63), x1c = min(max(x1, 0), 63);

    float4 wv4;
    wv4.x = (1.f - wy) * (1.f - wx) * vy0 * vx0 * mask;
    wv4.y = (1.f - wy) * wx * vy0 * vx1 * mask;
    wv4.z = wy * (1.f - wx) * vy1 * vx0 * mask;
    wv4.w = wy * wx * vy1 * vx1 * mask;
    uint4 ov;
    ov.x = (unsigned)(((y0c << 6) + x0c) << 8);
    ov.y = (unsigned)(((y0c << 6) + x1c) << 8);
    ov.z = (unsigned)(((y1c << 6) + x0c) << 8);
    ov.w = (unsigned)(((y1c << 6) + x1c) << 8);

    float* p = SW + (size_t)(k * 16384 + bhw) * 8;
    *(float4*)p = wv4;
    *(uint4*)(p + 4) = ov;
  }
}

// ---------------------------------------------------------------------------
// Kernel 3: fused sample + main GEMM, DEPTH-2 pipeline (round-2 best: 51.4us).
//  BM=256 x BN=64, BK=32, grid 256, XCD-swizzled blocks, 512 thr / 8 waves.
//  UNCHANGED from round 4 (control).
// ---------------------------------------------------------------------------
#define FSTEP(KT, Q, AF, BUF, DOSW)                                            \
  do {                                                                         \
    float s0_ = wv4.x * bf2f(Q[0].x) + wv4.y * bf2f(Q[1].x) +                  \
                wv4.z * bf2f(Q[2].x) + wv4.w * bf2f(Q[3].x);                   \
    float s1_ = wv4.x * bf2f(Q[0].y) + wv4.y * bf2f(Q[1].y) +                  \
                wv4.z * bf2f(Q[2].y) + wv4.w * bf2f(Q[3].y);                   \
    float s2_ = wv4.x * bf2f(Q[0].z) + wv4.y * bf2f(Q[1].z) +                  \
                wv4.z * bf2f(Q[2].z) + wv4.w * bf2f(Q[3].z);                   \
    float s3_ = wv4.x * bf2f(Q[0].w) + wv4.y * bf2f(Q[1].w) +                  \
                wv4.z * bf2f(Q[2].w) + wv4.w * bf2f(Q[3].w);                   \
    union { __hip_bfloat162 h2[2]; ushort4 v; } pk_;                           \
    pk_.h2[0] = __float22bfloat162_rn(make_float2(s0_, s1_));                  \
    pk_.h2[1] = __float22bfloat162_rn(make_float2(s2_, s3_));                  \
    *(ushort4*)(&Bs[BUF][bsw]) = pk_.v;                                        \
    if (DOSW && ((KT) & 7) == 0 && (KT) < 64) {                                \
      const float* swp_ =                                                      \
          SW + ((size_t)(((((KT) >> 3) + 1) << 14) + n0 + r)) * 8;             \
      wv4n = *(const float4*)swp_;                                             \
      ovn  = *(const uint4*)(swp_ + 4);                                        \
    }                                                                          \
    if ((KT) < 70) {                                                           \
      int kn_ = (KT) + 2;                                                      \
      uint4 o_ = (((KT) & 7) >= 6) ? ovn : ov;                                 \
      unsigned c_ = (unsigned)(((kn_ & 7) << 5) + ch0);                        \
      Q[0] = *(const ushort4*)(xb + o_.x + c_);                                \
      Q[1] = *(const ushort4*)(xb + o_.y + c_);                                \
      Q[2] = *(const ushort4*)(xb + o_.z + c_);                                \
      Q[3] = *(const ushort4*)(xb + o_.w + c_);                                \
    }                                                                          \
    asm volatile("s_waitcnt lgkmcnt(0)\n\ts_barrier" ::: "memory");            \
    bf16x8 bF0_ = *(const bf16x8*)(&Bs[BUF][(wn * 32 + (lane & 15)) * 40 +     \
                                            (lane >> 4) * 8]);                 \
    bf16x8 bF1_ = *(const bf16x8*)(&Bs[BUF][(wn * 32 + 16 + (lane & 15)) * 40 +\
                                            (lane >> 4) * 8]);                 \
    _Pragma("unroll")                                                          \
    for (int i_ = 0; i_ < 4; ++i_) {                                           \
      acc[i_][0] =                                                             \
          __builtin_amdgcn_mfma_f32_16x16x32_bf16(AF[i_], bF0_, acc[i_][0],    \
                                                  0, 0, 0);                    \
      acc[i_][1] =                                                             \
          __builtin_amdgcn_mfma_f32_16x16x32_bf16(AF[i_], bF1_, acc[i_][1],    \
                                                  0, 0, 0);                    \
    }                                                                          \
    if ((KT) < 70) {                                                           \
      int kn_ = (KT) + 2;                                                      \
      _Pragma("unroll")                                                        \
      for (int i_ = 0; i_ < 4; ++i_)                                           \
        AF[i_] = *(const bf16x8*)(wpBase + ((size_t)kn_ * 16 + i_) * 512);     \
    }                                                                          \
  } while (0)

__global__ __launch_bounds__(512) void k_fused(const unsigned short* __restrict__ Wpk,
                                               const unsigned short* __restrict__ xTb,
                                               const float* __restrict__ SW,
                                               float* __restrict__ out) {
  __shared__ __align__(16) unsigned short Bs[2][64 * 40];  // 10 KB
  int t = threadIdx.x;
  int wv = t >> 6, lane = t & 63;
  int wm = wv & 3, wn = wv >> 2;
  int bid = (int)blockIdx.x;
  int swz = (bid & 7) * 32 + (bid >> 3);   // XCD-contiguous chunks (256 = 8*32)
  int n0 = swz * 64;
  int b  = n0 >> 12;
  const unsigned short* xb = xTb + ((size_t)b << 20);

  // sampling role: row r (0..63), channel quad g (0..7) -> ch = g*4
  int r = t >> 3, g = t & 7;
  int ch0 = g * 4;
  int bsw = r * 40 + ch0;

  // A-fragment base: wave covers m-blocks wm*4 .. wm*4+3
  const unsigned short* wpBase = Wpk + ((size_t)(wm * 4 * 64 + lane)) * 8;

  f32x4 acc[4][2] = {};

  float4 wv4, wv4n; uint4 ov, ovn;
  {
    const float* sw = SW + ((size_t)(n0 + r)) * 8;
    wv4 = *(const float4*)sw;
    ov  = *(const uint4*)(sw + 4);
  }
  wv4n = wv4; ovn = ov;

  ushort4 qA[4], qB[4];
  bf16x8 aFA[4], aFB[4];

  // prologue: gathers for kt=0 (qA) and kt=1 (qB); A-fragments for kt=0,1
  {
    unsigned c0_ = (unsigned)ch0;
    qA[0] = *(const ushort4*)(xb + ov.x + c0_);
    qA[1] = *(const ushort4*)(xb + ov.y + c0_);
    qA[2] = *(const ushort4*)(xb + ov.z + c0_);
    qA[3] = *(const ushort4*)(xb + ov.w + c0_);
    unsigned c1_ = (unsigned)(32 + ch0);
    qB[0] = *(const ushort4*)(xb + ov.x + c1_);
    qB[1] = *(const ushort4*)(xb + ov.y + c1_);
    qB[2] = *(const ushort4*)(xb + ov.z + c1_);
    qB[3] = *(const ushort4*)(xb + ov.w + c1_);
#pragma unroll
    for (int i = 0; i < 4; ++i) {
      aFA[i] = *(const bf16x8*)(wpBase + (size_t)i * 512);
      aFB[i] = *(const bf16x8*)(wpBase + (size_t)(16 + i) * 512);
    }
  }

  for (int kt = 0; kt < 72; kt += 2) {
    FSTEP(kt,     qA, aFA, 0, 1);
    FSTEP(kt + 1, qB, aFB, 1, 0);
    if ((kt & 7) == 6) { wv4 = wv4n; ov = ovn; }  // rotate after group end
  }

  // epilogue
  int quad = lane >> 4, cl = lane & 15;
  float* ob = out + (((size_t)b) << 20);
#pragma unroll
  for (int i = 0; i < 4; ++i) {
    int mbase = wm * 64 + i * 16 + quad * 4;
#pragma unroll
    for (int j = 0; j < 2; ++j) {
      int hw = (n0 & 4095) + wn * 32 + j * 16 + cl;
      float* op = ob + hw;
#pragma unroll
      for (int rr = 0; rr < 4; ++rr)
        op[((size_t)(mbase + rr)) << 12] = acc[i][j][rr];
    }
  }
}

// ---------------------------------------------------------------------------
extern "C" void kernel_launch(void* const* d_in, const int* in_sizes, int n_in,
                              void* d_out, int out_size, void* d_ws, size_t ws_size,
                              hipStream_t stream) {
  const float* x        = (const float*)d_in[0];
  const float* offset_w = (const float*)d_in[1];
  const float* offset_b = (const float*)d_in[2];
  const float* dcn_w    = (const float*)d_in[3];
  float* out = (float*)d_out;

  char* ws = (char*)d_ws;
  size_t off = 0;
  auto carve = [&](size_t bytes) -> void* {
    void* p = ws + off;
    off += (bytes + 255) & ~(size_t)255;
    return p;
  };
  unsigned short* xTb = (unsigned short*)carve(4ull * 64 * 64 * 256 * 2);   // 8 MB
  unsigned short* Wpk = (unsigned short*)carve(72ull * 8192 * 2);           // 1.125 MB
  unsigned short* Wob = (unsigned short*)carve(32ull * KDIM * 2);           // 144 KB
  unsigned short* zp  = (unsigned short*)carve(256);                        // zero page
  float*          SW  = (float*)carve(9ull * 16384 * 8 * 4);                // 4.5 MB
  (void)ws_size; (void)in_sizes; (void)n_in; (void)out_size;

  // prep grid: 2048 transpose blocks + ceil((72*8192 + 32*KDIM + 128)/256)
  const int WPREP_BLOCKS = (72 * 8192 + 32 * KDIM + 128 + 255) / 256;
  k_prep<<<dim3(2048 + WPREP_BLOCKS), 256, 0, stream>>>(
      x, xTb, dcn_w, offset_w, Wpk, Wob, zp);
  k_offs<<<dim3(512), 256, 0, stream>>>(xTb, Wob, zp, offset_b, SW);
  k_fused<<<dim3(256), 512, 0, stream>>>(Wpk, xTb, SW, out);
}

// Round 6
// 135.590 us; speedup vs baseline: 1.1514x; 1.0539x over previous
//
#include <hip/hip_runtime.h>
#include <hip/hip_bf16.h>
#include <stdint.h>
#include <math.h>

#define KDIM 2304   // 9 * 256

typedef __attribute__((ext_vector_type(8))) short bf16x8;
typedef __attribute__((ext_vector_type(4))) float f32x4;

__device__ inline unsigned short f2bf(float f) {
  union { float f; unsigned int u; } v; v.f = f;
  unsigned int u = v.u;
  unsigned int r = (u + 0x7FFFu + ((u >> 16) & 1u)) >> 16;
  return (unsigned short)r;
}
__device__ inline float bf2f(unsigned short h) {
  union { unsigned int u; float f; } v; v.u = ((unsigned int)h) << 16;
  return v.f;
}

__device__ inline void gl2lds16(const void* g, void* l) {
  __builtin_amdgcn_global_load_lds((const __attribute__((address_space(1))) void*)g,
                                   (__attribute__((address_space(3))) void*)l,
                                   16, 0, 0);
}

// ---------------------------------------------------------------------------
// Kernel 1: fused prep (unchanged from round 5).
// ---------------------------------------------------------------------------
__global__ __launch_bounds__(256) void k_prep(const float* __restrict__ x,
                                              unsigned short* __restrict__ xTb,
                                              const float* __restrict__ dcn_w,
                                              const float* __restrict__ offset_w,
                                              unsigned short* __restrict__ Wpk,
                                              unsigned short* __restrict__ Wob,
                                              unsigned short* __restrict__ zp) {
  __shared__ float tile[32][65];
  int bx = (int)blockIdx.x;
  int t = threadIdx.x;
  if (bx < 2048) {
    int pt = bx & 127, ct = (bx >> 7) & 3, b = bx >> 9;
    int p0 = pt * 32, c0 = ct * 64;
    const float* xb = x + ((size_t)b << 20);
#pragma unroll
    for (int i = 0; i < 2; ++i) {
      int idx = t + i * 256;
      int c = idx >> 3, pq = idx & 7;
      float4 v = *(const float4*)(xb + ((size_t)(c0 + c) << 12) + p0 + pq * 4);
      tile[pq * 4 + 0][c] = v.x;
      tile[pq * 4 + 1][c] = v.y;
      tile[pq * 4 + 2][c] = v.z;
      tile[pq * 4 + 3][c] = v.w;
    }
    __syncthreads();
    unsigned short* ob = xTb + ((size_t)b << 20);
#pragma unroll
    for (int i = 0; i < 2; ++i) {
      int idx = t + i * 256;
      int p = idx >> 4, cg = idx & 15;
      ushort4 o;
      o.x = f2bf(tile[p][cg * 4 + 0]);
      o.y = f2bf(tile[p][cg * 4 + 1]);
      o.z = f2bf(tile[p][cg * 4 + 2]);
      o.w = f2bf(tile[p][cg * 4 + 3]);
      *(ushort4*)(ob + (((size_t)(p0 + p)) << 8) + c0 + cg * 4) = o;
    }
  } else {
    int gid = (bx - 2048) * 256 + t;
    const int N1 = 72 * 8192;
    const int N2 = 32 * KDIM;
    if (gid < N1) {
      int j = gid & 7;
      int lane = (gid >> 3) & 63;
      int mb = (gid >> 9) & 15;
      int kc = gid >> 13;
      int row = mb * 16 + (lane & 15);
      int gk = kc * 32 + ((lane >> 4) << 3) + j;
      int c = gk & 255, kidx = gk >> 8;
      Wpk[gid] = f2bf(dcn_w[((size_t)(row * 256 + c)) * 9 + kidx]);
    } else if (gid < N1 + N2) {
      int g = gid - N1;
      int ch = g / KDIM, k = g % KDIM;
      int kidx = k >> 8, c = k & 255;
      Wob[g] = (ch < 27) ? f2bf(offset_w[((size_t)(ch * 256 + c)) * 9 + kidx])
                         : (unsigned short)0;
    } else if (gid < N1 + N2 + 128) {
      zp[gid - N1 - N2] = 0;
    }
  }
}

// ---------------------------------------------------------------------------
// Kernel 2: offset conv GEMM + sampling-table epilogue (unchanged from R5).
// ---------------------------------------------------------------------------
__global__ __launch_bounds__(256) void k_offs(const unsigned short* __restrict__ xTb,
                                              const unsigned short* __restrict__ Wob,
                                              const unsigned short* __restrict__ zp,
                                              const float* __restrict__ offb,
                                              float* __restrict__ SW) {
  __shared__ unsigned short As[4][32 * 32];
  __shared__ unsigned short Bs[4][32 * 32];
  __shared__ float Os[32][33];
  int t = threadIdx.x;
  int wv = t >> 6, lane = t & 63;
  int bid = (int)blockIdx.x;
  int swz = (bid & 7) * 64 + (bid >> 3);
  int n0 = swz * 32;

  int r0 = (t >> 2) & 31, coff = (t & 3) * 8;
  int rowA = n0 + r0;
  int b_ = rowA >> 12, hw = rowA & 4095, h = hw >> 6, w = hw & 63;
  int rB = ((t - 128) >> 2) & 31;

  f32x4 acc = {};

  auto stage = [&](int kt) {
    int buf = kt & 3;
    int k0 = kt * 32;
    int kidx = k0 >> 8, c0 = k0 & 255;
    if (t < 128) {
      int di = kidx / 3 - 1, dj = kidx % 3 - 1;
      int y = h + di, xx = w + dj;
      const unsigned short* g = (y >= 0 && y < 64 && xx >= 0 && xx < 64)
          ? xTb + (((((size_t)b_) << 12) + (y << 6) + xx) << 8) + c0 + coff
          : zp;
      gl2lds16(g, (char*)As[buf] + wv * 1024);
    } else {
      const unsigned short* gB = Wob + (size_t)rB * KDIM + k0 + coff;
      gl2lds16(gB, (char*)Bs[buf] + (wv - 2) * 1024);
    }
  };

  stage(0); stage(1); stage(2);

  int mf = wv & 1, nf = wv >> 1;
  for (int kt = 0; kt < 72; ++kt) {
    if (kt <= 69)      asm volatile("s_waitcnt vmcnt(2)" ::: "memory");
    else if (kt == 70) asm volatile("s_waitcnt vmcnt(1)" ::: "memory");
    else               asm volatile("s_waitcnt vmcnt(0)" ::: "memory");
    asm volatile("s_barrier" ::: "memory");
    if (kt + 3 < 72) stage(kt + 3);
    int buf = kt & 3;
    bf16x8 aF = *(const bf16x8*)(As[buf] + (mf * 16 + (lane & 15)) * 32 + (lane >> 4) * 8);
    bf16x8 bF = *(const bf16x8*)(Bs[buf] + (nf * 16 + (lane & 15)) * 32 + (lane >> 4) * 8);
    acc = __builtin_amdgcn_mfma_f32_16x16x32_bf16(aF, bF, acc, 0, 0, 0);
  }

  int quad = lane >> 4, cl = lane & 15;
#pragma unroll
  for (int r = 0; r < 4; ++r)
    Os[mf * 16 + quad * 4 + r][nf * 16 + cl] = acc[r];
  __syncthreads();

  for (int item = t; item < 288; item += 256) {
    int bl = item & 31, k = item >> 5;
    int bhw = n0 + bl;
    int h_ = (bhw >> 6) & 63, w_ = bhw & 63;
    float dy = Os[bl][2 * k]     + offb[2 * k];
    float dx = Os[bl][2 * k + 1] + offb[2 * k + 1];
    float mv = Os[bl][18 + k]    + offb[18 + k];
    float mask = 1.0f / (1.0f + expf(-mv));

    float py = (float)(h_ - 1 + k / 3) + dy;
    float px = (float)(w_ - 1 + k % 3) + dx;
    float y0f = floorf(py), x0f = floorf(px);
    float wy = py - y0f, wx = px - x0f;
    int y0 = (int)y0f, x0 = (int)x0f;
    int y1 = y0 + 1, x1 = x0 + 1;

    float vy0 = (y0 >= 0 && y0 < 64) ? 1.f : 0.f;
    float vy1 = (y1 >= 0 && y1 < 64) ? 1.f : 0.f;
    float vx0 = (x0 >= 0 && x0 < 64) ? 1.f : 0.f;
    float vx1 = (x1 >= 0 && x1 < 64) ? 1.f : 0.f;
    int y0c = min(max(y0, 0), 63), y1c = min(max(y1, 0), 63);
    int x0c = min(max(x0, 0), 63), x1c = min(max(x1, 0), 63);

    float4 wv4;
    wv4.x = (1.f - wy) * (1.f - wx) * vy0 * vx0 * mask;
    wv4.y = (1.f - wy) * wx * vy0 * vx1 * mask;
    wv4.z = wy * (1.f - wx) * vy1 * vx0 * mask;
    wv4.w = wy * wx * vy1 * vx1 * mask;
    uint4 ov;
    ov.x = (unsigned)(((y0c << 6) + x0c) << 8);
    ov.y = (unsigned)(((y0c << 6) + x1c) << 8);
    ov.z = (unsigned)(((y1c << 6) + x0c) << 8);
    ov.w = (unsigned)(((y1c << 6) + x1c) << 8);

    float* p = SW + (size_t)(k * 16384 + bhw) * 8;
    *(float4*)p = wv4;
    *(uint4*)(p + 4) = ov;
  }
}

// ---------------------------------------------------------------------------
// Kernel 3: fused sample + main GEMM -- BK=64 PHASES (36 barriers, not 72),
//  __launch_bounds__(512,2) so the pipeline actually lives in registers.
//  BM=256 x BN=64, grid 256, XCD swizzle. Per phase: two 32-chunks.
//  Thread roles: r = t>>3 (row 0..63), u = t&7 -> substep s_th=u&1,
//  ch-group gg=u>>1 (8 channels). Gathers: 4 corners x 16B, 1 phase ahead.
//  LDS rows padded to 56 shorts (112B = odd multiple of 16B: aligned b128 +
//  2-way-max bank pattern).
// ---------------------------------------------------------------------------
#define PHASE(PH, Q, AF, BUF)                                                  \
  do {                                                                         \
    float s_[8];                                                               \
    _Pragma("unroll")                                                          \
    for (int j_ = 0; j_ < 8; ++j_)                                             \
      s_[j_] = wv4.x * bf2f((unsigned short)Q[0][j_]) +                        \
               wv4.y * bf2f((unsigned short)Q[1][j_]) +                        \
               wv4.z * bf2f((unsigned short)Q[2][j_]) +                        \
               wv4.w * bf2f((unsigned short)Q[3][j_]);                         \
    union { __hip_bfloat162 h2[4]; bf16x8 v; } pk_;                            \
    pk_.h2[0] = __float22bfloat162_rn(make_float2(s_[0], s_[1]));              \
    pk_.h2[1] = __float22bfloat162_rn(make_float2(s_[2], s_[3]));              \
    pk_.h2[2] = __float22bfloat162_rn(make_float2(s_[4], s_[5]));              \
    pk_.h2[3] = __float22bfloat162_rn(make_float2(s_[6], s_[7]));              \
    *(bf16x8*)(&Bs[BUF][s_th][bsw]) = pk_.v;                                   \
    if (((PH) & 3) == 0 && (PH) < 32) {                                        \
      const float* swp_ =                                                      \
          SW + ((size_t)((((PH) >> 2) + 1) * 16384 + n0 + r)) * 8;             \
      wv4n = *(const float4*)swp_;                                             \
      ovn  = *(const uint4*)(swp_ + 4);                                        \
    }                                                                          \
    if ((PH) < 34) {                                                           \
      int kn0_ = 2 * (PH) + 4;                                                 \
      uint4 o_ = (((PH) & 3) >= 2) ? ovn : ov;                                 \
      unsigned c_ = (unsigned)((((kn0_ & 7) + s_th) << 5) + gg * 8);           \
      Q[0] = *(const bf16x8*)(xb + o_.x + c_);                                 \
      Q[1] = *(const bf16x8*)(xb + o_.y + c_);                                 \
      Q[2] = *(const bf16x8*)(xb + o_.z + c_);                                 \
      Q[3] = *(const bf16x8*)(xb + o_.w + c_);                                 \
    }                                                                          \
    asm volatile("s_waitcnt lgkmcnt(0)\n\ts_barrier" ::: "memory");            \
    _Pragma("unroll")                                                          \
    for (int s2_ = 0; s2_ < 2; ++s2_) {                                        \
      bf16x8 bF0_ = *(const bf16x8*)(                                          \
          &Bs[BUF][s2_][(wn * 32 + (lane & 15)) * 56 + (lane >> 4) * 8]);      \
      bf16x8 bF1_ = *(const bf16x8*)(                                          \
          &Bs[BUF][s2_][(wn * 32 + 16 + (lane & 15)) * 56 + (lane >> 4) * 8]); \
      _Pragma("unroll")                                                        \
      for (int i_ = 0; i_ < 4; ++i_) {                                         \
        acc[i_][0] = __builtin_amdgcn_mfma_f32_16x16x32_bf16(                  \
            AF[s2_ * 4 + i_], bF0_, acc[i_][0], 0, 0, 0);                      \
        acc[i_][1] = __builtin_amdgcn_mfma_f32_16x16x32_bf16(                  \
            AF[s2_ * 4 + i_], bF1_, acc[i_][1], 0, 0, 0);                      \
      }                                                                        \
    }                                                                          \
    if ((PH) < 34) {                                                           \
      _Pragma("unroll")                                                        \
      for (int i_ = 0; i_ < 8; ++i_)                                           \
        AF[i_] = *(const bf16x8*)(                                             \
            wpBase + ((size_t)((2 * (PH) + 4 + (i_ >> 2)) * 16 + (i_ & 3))) * 512); \
    }                                                                          \
  } while (0)

__global__ __launch_bounds__(512, 2) void k_fused(const unsigned short* __restrict__ Wpk,
                                                  const unsigned short* __restrict__ xTb,
                                                  const float* __restrict__ SW,
                                                  float* __restrict__ out) {
  __shared__ __align__(16) unsigned short Bs[2][2][64 * 56];  // 28 KB
  int t = threadIdx.x;
  int wv = t >> 6, lane = t & 63;
  int wm = wv & 3, wn = wv >> 2;
  int bid = (int)blockIdx.x;
  int swz = (bid & 7) * 32 + (bid >> 3);   // XCD-contiguous chunks (256 = 8*32)
  int n0 = swz * 64;
  int b  = n0 >> 12;
  const unsigned short* xb = xTb + ((size_t)b << 20);

  // sampling role: row r (0..63); u = t&7 -> substep s_th, ch-group gg (8 ch)
  int r = t >> 3;
  int u = t & 7;
  int s_th = u & 1, gg = u >> 1;
  int bsw = r * 56 + gg * 8;

  // A-fragment base: wave covers m-blocks wm*4 .. wm*4+3
  const unsigned short* wpBase = Wpk + ((size_t)(wm * 4 * 64 + lane)) * 8;

  f32x4 acc[4][2] = {};

  float4 wv4, wv4n; uint4 ov, ovn;
  {
    const float* sw = SW + ((size_t)(n0 + r)) * 8;
    wv4 = *(const float4*)sw;
    ov  = *(const uint4*)(sw + 4);
  }
  wv4n = wv4; ovn = ov;

  bf16x8 qA[4], qB[4];
  bf16x8 aFA[8], aFB[8];

  // prologue: gathers for phase 0 (kt 0,1) and phase 1 (kt 2,3); A-frags
  {
    unsigned cA = (unsigned)((s_th << 5) + gg * 8);
    unsigned cB = (unsigned)(((2 + s_th) << 5) + gg * 8);
    qA[0] = *(const bf16x8*)(xb + ov.x + cA);
    qA[1] = *(const bf16x8*)(xb + ov.y + cA);
    qA[2] = *(const bf16x8*)(xb + ov.z + cA);
    qA[3] = *(const bf16x8*)(xb + ov.w + cA);
    qB[0] = *(const bf16x8*)(xb + ov.x + cB);
    qB[1] = *(const bf16x8*)(xb + ov.y + cB);
    qB[2] = *(const bf16x8*)(xb + ov.z + cB);
    qB[3] = *(const bf16x8*)(xb + ov.w + cB);
#pragma unroll
    for (int i = 0; i < 8; ++i) {
      aFA[i] = *(const bf16x8*)(wpBase + ((size_t)(((i >> 2)) * 16 + (i & 3))) * 512);
      aFB[i] = *(const bf16x8*)(wpBase + ((size_t)((2 + (i >> 2)) * 16 + (i & 3))) * 512);
    }
  }

  for (int ph = 0; ph < 36; ph += 2) {
    PHASE(ph,     qA, aFA, 0);
    PHASE(ph + 1, qB, aFB, 1);
    if ((ph & 3) == 2) { wv4 = wv4n; ov = ovn; }  // rotate at k-group boundary
  }

  // epilogue
  int quad = lane >> 4, cl = lane & 15;
  float* ob = out + (((size_t)b) << 20);
#pragma unroll
  for (int i = 0; i < 4; ++i) {
    int mbase = wm * 64 + i * 16 + quad * 4;
#pragma unroll
    for (int j = 0; j < 2; ++j) {
      int hw = (n0 & 4095) + wn * 32 + j * 16 + cl;
      float* op = ob + hw;
#pragma unroll
      for (int rr = 0; rr < 4; ++rr)
        op[((size_t)(mbase + rr)) << 12] = acc[i][j][rr];
    }
  }
}

// ---------------------------------------------------------------------------
extern "C" void kernel_launch(void* const* d_in, const int* in_sizes, int n_in,
                              void* d_out, int out_size, void* d_ws, size_t ws_size,
                              hipStream_t stream) {
  const float* x        = (const float*)d_in[0];
  const float* offset_w = (const float*)d_in[1];
  const float* offset_b = (const float*)d_in[2];
  const float* dcn_w    = (const float*)d_in[3];
  float* out = (float*)d_out;

  char* ws = (char*)d_ws;
  size_t off = 0;
  auto carve = [&](size_t bytes) -> void* {
    void* p = ws + off;
    off += (bytes + 255) & ~(size_t)255;
    return p;
  };
  unsigned short* xTb = (unsigned short*)carve(4ull * 64 * 64 * 256 * 2);   // 8 MB
  unsigned short* Wpk = (unsigned short*)carve(72ull * 8192 * 2);           // 1.125 MB
  unsigned short* Wob = (unsigned short*)carve(32ull * KDIM * 2);           // 144 KB
  unsigned short* zp  = (unsigned short*)carve(256);                        // zero page
  float*          SW  = (float*)carve(9ull * 16384 * 8 * 4);                // 4.5 MB
  (void)ws_size; (void)in_sizes; (void)n_in; (void)out_size;

  const int WPREP_BLOCKS = (72 * 8192 + 32 * KDIM + 128 + 255) / 256;
  k_prep<<<dim3(2048 + WPREP_BLOCKS), 256, 0, stream>>>(
      x, xTb, dcn_w, offset_w, Wpk, Wob, zp);
  k_offs<<<dim3(512), 256, 0, stream>>>(xTb, Wob, zp, offset_b, SW);
  k_fused<<<dim3(256), 512, 0, stream>>>(Wpk, xTb, SW, out);
}

// Round 7
// 131.590 us; speedup vs baseline: 1.1864x; 1.0304x over previous
//
#include <hip/hip_runtime.h>
#include <hip/hip_bf16.h>
#include <stdint.h>
#include <math.h>

#define KDIM 2304   // 9 * 256

typedef __attribute__((ext_vector_type(8))) short bf16x8;
typedef __attribute__((ext_vector_type(4))) float f32x4;

__device__ inline unsigned short f2bf(float f) {
  union { float f; unsigned int u; } v; v.f = f;
  unsigned int u = v.u;
  unsigned int r = (u + 0x7FFFu + ((u >> 16) & 1u)) >> 16;
  return (unsigned short)r;
}
__device__ inline float bf2f(unsigned short h) {
  union { unsigned int u; float f; } v; v.u = ((unsigned int)h) << 16;
  return v.f;
}

__device__ inline void gl2lds16(const void* g, void* l) {
  __builtin_amdgcn_global_load_lds((const __attribute__((address_space(1))) void*)g,
                                   (__attribute__((address_space(3))) void*)l,
                                   16, 0, 0);
}

// volatile asm load: compiler cannot sink it, "=v" forces the live range.
#define GLOAD16(dst, ptr) \
  asm volatile("global_load_dwordx4 %0, %1, off" : "=v"(dst) : "v"(ptr))

// ---------------------------------------------------------------------------
// Kernel 1: fused prep (unchanged from round 5/6).
// ---------------------------------------------------------------------------
__global__ __launch_bounds__(256) void k_prep(const float* __restrict__ x,
                                              unsigned short* __restrict__ xTb,
                                              const float* __restrict__ dcn_w,
                                              const float* __restrict__ offset_w,
                                              unsigned short* __restrict__ Wpk,
                                              unsigned short* __restrict__ Wob,
                                              unsigned short* __restrict__ zp) {
  __shared__ float tile[32][65];
  int bx = (int)blockIdx.x;
  int t = threadIdx.x;
  if (bx < 2048) {
    int pt = bx & 127, ct = (bx >> 7) & 3, b = bx >> 9;
    int p0 = pt * 32, c0 = ct * 64;
    const float* xb = x + ((size_t)b << 20);
#pragma unroll
    for (int i = 0; i < 2; ++i) {
      int idx = t + i * 256;
      int c = idx >> 3, pq = idx & 7;
      float4 v = *(const float4*)(xb + ((size_t)(c0 + c) << 12) + p0 + pq * 4);
      tile[pq * 4 + 0][c] = v.x;
      tile[pq * 4 + 1][c] = v.y;
      tile[pq * 4 + 2][c] = v.z;
      tile[pq * 4 + 3][c] = v.w;
    }
    __syncthreads();
    unsigned short* ob = xTb + ((size_t)b << 20);
#pragma unroll
    for (int i = 0; i < 2; ++i) {
      int idx = t + i * 256;
      int p = idx >> 4, cg = idx & 15;
      ushort4 o;
      o.x = f2bf(tile[p][cg * 4 + 0]);
      o.y = f2bf(tile[p][cg * 4 + 1]);
      o.z = f2bf(tile[p][cg * 4 + 2]);
      o.w = f2bf(tile[p][cg * 4 + 3]);
      *(ushort4*)(ob + (((size_t)(p0 + p)) << 8) + c0 + cg * 4) = o;
    }
  } else {
    int gid = (bx - 2048) * 256 + t;
    const int N1 = 72 * 8192;
    const int N2 = 32 * KDIM;
    if (gid < N1) {
      int j = gid & 7;
      int lane = (gid >> 3) & 63;
      int mb = (gid >> 9) & 15;
      int kc = gid >> 13;
      int row = mb * 16 + (lane & 15);
      int gk = kc * 32 + ((lane >> 4) << 3) + j;
      int c = gk & 255, kidx = gk >> 8;
      Wpk[gid] = f2bf(dcn_w[((size_t)(row * 256 + c)) * 9 + kidx]);
    } else if (gid < N1 + N2) {
      int g = gid - N1;
      int ch = g / KDIM, k = g % KDIM;
      int kidx = k >> 8, c = k & 255;
      Wob[g] = (ch < 27) ? f2bf(offset_w[((size_t)(ch * 256 + c)) * 9 + kidx])
                         : (unsigned short)0;
    } else if (gid < N1 + N2 + 128) {
      zp[gid - N1 - N2] = 0;
    }
  }
}

// ---------------------------------------------------------------------------
// Kernel 2: offset conv GEMM + sampling-table epilogue (unchanged from R5/R6).
// ---------------------------------------------------------------------------
__global__ __launch_bounds__(256) void k_offs(const unsigned short* __restrict__ xTb,
                                              const unsigned short* __restrict__ Wob,
                                              const unsigned short* __restrict__ zp,
                                              const float* __restrict__ offb,
                                              float* __restrict__ SW) {
  __shared__ unsigned short As[4][32 * 32];
  __shared__ unsigned short Bs[4][32 * 32];
  __shared__ float Os[32][33];
  int t = threadIdx.x;
  int wv = t >> 6, lane = t & 63;
  int bid = (int)blockIdx.x;
  int swz = (bid & 7) * 64 + (bid >> 3);
  int n0 = swz * 32;

  int r0 = (t >> 2) & 31, coff = (t & 3) * 8;
  int rowA = n0 + r0;
  int b_ = rowA >> 12, hw = rowA & 4095, h = hw >> 6, w = hw & 63;
  int rB = ((t - 128) >> 2) & 31;

  f32x4 acc = {};

  auto stage = [&](int kt) {
    int buf = kt & 3;
    int k0 = kt * 32;
    int kidx = k0 >> 8, c0 = k0 & 255;
    if (t < 128) {
      int di = kidx / 3 - 1, dj = kidx % 3 - 1;
      int y = h + di, xx = w + dj;
      const unsigned short* g = (y >= 0 && y < 64 && xx >= 0 && xx < 64)
          ? xTb + (((((size_t)b_) << 12) + (y << 6) + xx) << 8) + c0 + coff
          : zp;
      gl2lds16(g, (char*)As[buf] + wv * 1024);
    } else {
      const unsigned short* gB = Wob + (size_t)rB * KDIM + k0 + coff;
      gl2lds16(gB, (char*)Bs[buf] + (wv - 2) * 1024);
    }
  };

  stage(0); stage(1); stage(2);

  int mf = wv & 1, nf = wv >> 1;
  for (int kt = 0; kt < 72; ++kt) {
    if (kt <= 69)      asm volatile("s_waitcnt vmcnt(2)" ::: "memory");
    else if (kt == 70) asm volatile("s_waitcnt vmcnt(1)" ::: "memory");
    else               asm volatile("s_waitcnt vmcnt(0)" ::: "memory");
    asm volatile("s_barrier" ::: "memory");
    if (kt + 3 < 72) stage(kt + 3);
    int buf = kt & 3;
    bf16x8 aF = *(const bf16x8*)(As[buf] + (mf * 16 + (lane & 15)) * 32 + (lane >> 4) * 8);
    bf16x8 bF = *(const bf16x8*)(Bs[buf] + (nf * 16 + (lane & 15)) * 32 + (lane >> 4) * 8);
    acc = __builtin_amdgcn_mfma_f32_16x16x32_bf16(aF, bF, acc, 0, 0, 0);
  }

  int quad = lane >> 4, cl = lane & 15;
#pragma unroll
  for (int r = 0; r < 4; ++r)
    Os[mf * 16 + quad * 4 + r][nf * 16 + cl] = acc[r];
  __syncthreads();

  for (int item = t; item < 288; item += 256) {
    int bl = item & 31, k = item >> 5;
    int bhw = n0 + bl;
    int h_ = (bhw >> 6) & 63, w_ = bhw & 63;
    float dy = Os[bl][2 * k]     + offb[2 * k];
    float dx = Os[bl][2 * k + 1] + offb[2 * k + 1];
    float mv = Os[bl][18 + k]    + offb[18 + k];
    float mask = 1.0f / (1.0f + expf(-mv));

    float py = (float)(h_ - 1 + k / 3) + dy;
    float px = (float)(w_ - 1 + k % 3) + dx;
    float y0f = floorf(py), x0f = floorf(px);
    float wy = py - y0f, wx = px - x0f;
    int y0 = (int)y0f, x0 = (int)x0f;
    int y1 = y0 + 1, x1 = x0 + 1;

    float vy0 = (y0 >= 0 && y0 < 64) ? 1.f : 0.f;
    float vy1 = (y1 >= 0 && y1 < 64) ? 1.f : 0.f;
    float vx0 = (x0 >= 0 && x0 < 64) ? 1.f : 0.f;
    float vx1 = (x1 >= 0 && x1 < 64) ? 1.f : 0.f;
    int y0c = min(max(y0, 0), 63), y1c = min(max(y1, 0), 63);
    int x0c = min(max(x0, 0), 63), x1c = min(max(x1, 0), 63);

    float4 wv4;
    wv4.x = (1.f - wy) * (1.f - wx) * vy0 * vx0 * mask;
    wv4.y = (1.f - wy) * wx * vy0 * vx1 * mask;
    wv4.z = wy * (1.f - wx) * vy1 * vx0 * mask;
    wv4.w = wy * wx * vy1 * vx1 * mask;
    uint4 ov;
    ov.x = (unsigned)(((y0c << 6) + x0c) << 8);
    ov.y = (unsigned)(((y0c << 6) + x1c) << 8);
    ov.z = (unsigned)(((y1c << 6) + x0c) << 8);
    ov.w = (unsigned)(((y1c << 6) + x1c) << 8);

    float* p = SW + (size_t)(k * 16384 + bhw) * 8;
    *(float4*)p = wv4;
    *(uint4*)(p + 4) = ov;
  }
}

// ---------------------------------------------------------------------------
// Kernel 3: fused sample + main GEMM, BK=64 phases, COMPILER-PROOF pipeline.
//  All steady-state global loads = volatile asm global_load_dwordx4 with
//  counted vmcnt (WB before blend, WM merged into pre-MFMA barrier) +
//  sched_barrier(0) fences (rule #18). SW table staged to LDS at entry so
//  the vmcnt arithmetic is exact (zero compiler VMEM in the loop).
//  Issue order per phase p: [SW ds_reads] WB-wait, blend(p), q(p+2) loads,
//  WM-wait+lgkm+barrier, bF ds_reads + 16 MFMA, aF(p+2) loads.
//  Steady counts: WB: newer-than-q(p) = aF(p)8 + q(p+1)4 + aF(p+1)8 = 20.
//                 WM: newer-than-aF(p) = q(p+1)4 + aF(p+1)8 + q(p+2)4 = 16.
// ---------------------------------------------------------------------------
#define PHASE(PH, Q, AF, BUF, WB, WM)                                          \
  do {                                                                         \
    if (((PH) & 3) == 0) {                                                     \
      int g_ = (PH) >> 2;                                                      \
      wv4 = *(const float4*)(SWL + (size_t)(g_ * 128 + r * 2) * 4);            \
      ov  = *(const uint4*)(SWL + (size_t)(g_ * 128 + r * 2 + 1) * 4);         \
    } else if (((PH) & 3) == 2 && (PH) < 32) {                                 \
      ov  = *(const uint4*)(SWL + (size_t)((((PH) >> 2) + 1) * 128 + r * 2 + 1) * 4); \
    }                                                                          \
    asm volatile("s_waitcnt vmcnt(" #WB ")" ::: "memory");                     \
    __builtin_amdgcn_sched_barrier(0);                                         \
    float s_[8];                                                               \
    _Pragma("unroll")                                                          \
    for (int j_ = 0; j_ < 8; ++j_)                                             \
      s_[j_] = wv4.x * bf2f((unsigned short)Q[0][j_]) +                        \
               wv4.y * bf2f((unsigned short)Q[1][j_]) +                        \
               wv4.z * bf2f((unsigned short)Q[2][j_]) +                        \
               wv4.w * bf2f((unsigned short)Q[3][j_]);                         \
    union { __hip_bfloat162 h2[4]; bf16x8 v; } pk_;                            \
    pk_.h2[0] = __float22bfloat162_rn(make_float2(s_[0], s_[1]));              \
    pk_.h2[1] = __float22bfloat162_rn(make_float2(s_[2], s_[3]));              \
    pk_.h2[2] = __float22bfloat162_rn(make_float2(s_[4], s_[5]));              \
    pk_.h2[3] = __float22bfloat162_rn(make_float2(s_[6], s_[7]));              \
    *(bf16x8*)(&Bs[BUF][s_th][bsw]) = pk_.v;                                   \
    if ((PH) < 34) {                                                           \
      int kn0_ = 2 * (PH) + 4;                                                 \
      unsigned c_ = (unsigned)((((kn0_ & 7) + s_th) << 5) + gg * 8);           \
      GLOAD16(Q[0], xb + ov.x + c_);                                           \
      GLOAD16(Q[1], xb + ov.y + c_);                                           \
      GLOAD16(Q[2], xb + ov.z + c_);                                           \
      GLOAD16(Q[3], xb + ov.w + c_);                                           \
    }                                                                          \
    asm volatile("s_waitcnt vmcnt(" #WM ") lgkmcnt(0)\n\ts_barrier" ::: "memory"); \
    __builtin_amdgcn_sched_barrier(0);                                         \
    _Pragma("unroll")                                                          \
    for (int s2_ = 0; s2_ < 2; ++s2_) {                                        \
      bf16x8 bF0_ = *(const bf16x8*)(                                          \
          &Bs[BUF][s2_][(wn * 32 + (lane & 15)) * 56 + (lane >> 4) * 8]);      \
      bf16x8 bF1_ = *(const bf16x8*)(                                          \
          &Bs[BUF][s2_][(wn * 32 + 16 + (lane & 15)) * 56 + (lane >> 4) * 8]); \
      _Pragma("unroll")                                                        \
      for (int i_ = 0; i_ < 4; ++i_) {                                         \
        acc[i_][0] = __builtin_amdgcn_mfma_f32_16x16x32_bf16(                  \
            AF[s2_ * 4 + i_], bF0_, acc[i_][0], 0, 0, 0);                      \
        acc[i_][1] = __builtin_amdgcn_mfma_f32_16x16x32_bf16(                  \
            AF[s2_ * 4 + i_], bF1_, acc[i_][1], 0, 0, 0);                      \
      }                                                                        \
    }                                                                          \
    if ((PH) < 34) {                                                           \
      _Pragma("unroll")                                                        \
      for (int i_ = 0; i_ < 8; ++i_) {                                         \
        const unsigned short* ap_ =                                            \
            wpBase + ((size_t)((2 * (PH) + 4 + (i_ >> 2)) * 16 + (i_ & 3))) * 512; \
        GLOAD16(AF[i_], ap_);                                                  \
      }                                                                        \
    }                                                                          \
  } while (0)

__global__ __launch_bounds__(512, 2) void k_fused(const unsigned short* __restrict__ Wpk,
                                                  const unsigned short* __restrict__ xTb,
                                                  const float* __restrict__ SW,
                                                  float* __restrict__ out) {
  __shared__ __align__(16) unsigned short Bs[2][2][64 * 56];  // 28 KB
  __shared__ __align__(16) float SWL[1152 * 4];               // 18 KB
  int t = threadIdx.x;
  int wv = t >> 6, lane = t & 63;
  int wm = wv & 3, wn = wv >> 2;
  int bid = (int)blockIdx.x;
  int swz = (bid & 7) * 32 + (bid >> 3);   // XCD-contiguous chunks (256 = 8*32)
  int n0 = swz * 64;
  int b  = n0 >> 12;
  const unsigned short* xb = xTb + ((size_t)b << 20);

  // sampling role: row r (0..63); u = t&7 -> substep s_th, ch-group gg (8 ch)
  int r = t >> 3;
  int u = t & 7;
  int s_th = u & 1, gg = u >> 1;
  int bsw = r * 56 + gg * 8;

  const unsigned short* wpBase = Wpk + ((size_t)(wm * 4 * 64 + lane)) * 8;

  f32x4 acc[4][2] = {};

  // --- stage SW table (64 rows x 9 groups x 32B = 18KB) into LDS ---
  {
#pragma unroll
    for (int i = 0; i < 3; ++i) {
      int hs = t + i * 512;                 // halfslot: grp*128 + row*2 + h
      if (hs < 1152) {                      // i=2: t<128 -> waves 0,1 (uniform)
        int grp = hs >> 7, row = (hs >> 1) & 63, hh = hs & 1;
        const float* src = SW + ((size_t)(grp * 16384 + n0 + row)) * 8 + hh * 4;
        char* dstbase = (char*)SWL + ((size_t)((t & ~63) + i * 512)) * 16;  // wave-uniform
        gl2lds16(src, dstbase);
      }
    }
  }
  asm volatile("s_waitcnt vmcnt(0)" ::: "memory");
  __builtin_amdgcn_s_barrier();

  float4 wv4; uint4 ov;
  wv4 = *(const float4*)(SWL + (size_t)(r * 2) * 4);
  ov  = *(const uint4*)(SWL + (size_t)(r * 2 + 1) * 4);

  bf16x8 qA[4], qB[4];
  bf16x8 aFA[8], aFB[8];

  // prologue loads in canonical order: q(0), aF(0), q(1), aF(1)
  {
    unsigned cA = (unsigned)((s_th << 5) + gg * 8);
    GLOAD16(qA[0], xb + ov.x + cA);
    GLOAD16(qA[1], xb + ov.y + cA);
    GLOAD16(qA[2], xb + ov.z + cA);
    GLOAD16(qA[3], xb + ov.w + cA);
#pragma unroll
    for (int i = 0; i < 8; ++i) {
      const unsigned short* ap = wpBase + ((size_t)(((i >> 2)) * 16 + (i & 3))) * 512;
      GLOAD16(aFA[i], ap);
    }
    unsigned cB = (unsigned)(((2 + s_th) << 5) + gg * 8);
    GLOAD16(qB[0], xb + ov.x + cB);
    GLOAD16(qB[1], xb + ov.y + cB);
    GLOAD16(qB[2], xb + ov.z + cB);
    GLOAD16(qB[3], xb + ov.w + cB);
#pragma unroll
    for (int i = 0; i < 8; ++i) {
      const unsigned short* ap = wpBase + ((size_t)((2 + (i >> 2)) * 16 + (i & 3))) * 512;
      GLOAD16(aFB[i], ap);
    }
  }

  for (int ph = 0; ph < 34; ph += 2) {       // phases 0..33
    PHASE(ph,     qA, aFA, 0, 20, 16);
    PHASE(ph + 1, qB, aFB, 1, 20, 16);
  }
  PHASE(34, qA, aFA, 0, 20, 12);
  PHASE(35, qB, aFB, 1, 8, 0);

  // epilogue
  int quad = lane >> 4, cl = lane & 15;
  float* ob = out + (((size_t)b) << 20);
#pragma unroll
  for (int i = 0; i < 4; ++i) {
    int mbase = wm * 64 + i * 16 + quad * 4;
#pragma unroll
    for (int j = 0; j < 2; ++j) {
      int hw = (n0 & 4095) + wn * 32 + j * 16 + cl;
      float* op = ob + hw;
#pragma unroll
      for (int rr = 0; rr < 4; ++rr)
        op[((size_t)(mbase + rr)) << 12] = acc[i][j][rr];
    }
  }
}

// ---------------------------------------------------------------------------
extern "C" void kernel_launch(void* const* d_in, const int* in_sizes, int n_in,
                              void* d_out, int out_size, void* d_ws, size_t ws_size,
                              hipStream_t stream) {
  const float* x        = (const float*)d_in[0];
  const float* offset_w = (const float*)d_in[1];
  const float* offset_b = (const float*)d_in[2];
  const float* dcn_w    = (const float*)d_in[3];
  float* out = (float*)d_out;

  char* ws = (char*)d_ws;
  size_t off = 0;
  auto carve = [&](size_t bytes) -> void* {
    void* p = ws + off;
    off += (bytes + 255) & ~(size_t)255;
    return p;
  };
  unsigned short* xTb = (unsigned short*)carve(4ull * 64 * 64 * 256 * 2);   // 8 MB
  unsigned short* Wpk = (unsigned short*)carve(72ull * 8192 * 2);           // 1.125 MB
  unsigned short* Wob = (unsigned short*)carve(32ull * KDIM * 2);           // 144 KB
  unsigned short* zp  = (unsigned short*)carve(256);                        // zero page
  float*          SW  = (float*)carve(9ull * 16384 * 8 * 4);                // 4.5 MB
  (void)ws_size; (void)in_sizes; (void)n_in; (void)out_size;

  const int WPREP_BLOCKS = (72 * 8192 + 32 * KDIM + 128 + 255) / 256;
  k_prep<<<dim3(2048 + WPREP_BLOCKS), 256, 0, stream>>>(
      x, xTb, dcn_w, offset_w, Wpk, Wob, zp);
  k_offs<<<dim3(512), 256, 0, stream>>>(xTb, Wob, zp, offset_b, SW);
  k_fused<<<dim3(256), 512, 0, stream>>>(Wpk, xTb, SW, out);
}